// Round 12
// baseline (121.807 us; speedup 1.0000x reference)
//
#include <hip/hip_runtime.h>

#define N_NODES 100000
#define N_EDGES 1600000
#define NCOARSE 391     // ceil(100000/256) coarse bins of 256 dst nodes
#define CB_NODES 256
#define NSLOTS  (NCOARSE * CB_NODES)  // 100096 slots (degree-sorted within bin)
#define CSTRIPE 8       // XCD-local striping of cursors + regions
#define CCAP    704     // per-(bin,stripe) capacity (mean 512, +8.5 sigma)
#define CSTRIDE 5632    // per-bin region stride = CSTRIPE*CCAP
#define BCHUNKS 512     // edge chunks (2 blocks/CU for latency hiding)
#define BCHUNK  3125    // N_EDGES/BCHUNKS exactly
#define NSTRIPS 6250    // N_NODES/16 row strips for MFMA gemm1

typedef short short8 __attribute__((ext_vector_type(8)));
typedef float f32x4 __attribute__((ext_vector_type(4)));
union Frag { uint4 q; short8 s; };

__device__ inline unsigned short f2bf(float f) {  // RNE f32 -> bf16
    unsigned u = __float_as_uint(f);
    unsigned r = u + 0x7fffu + ((u >> 16) & 1u);
    return (unsigned short)(r >> 16);
}
__device__ inline unsigned pk2(float lo, float hi) {
    return (unsigned)f2bf(lo) | ((unsigned)f2bf(hi) << 16);
}
__device__ inline float bflo(unsigned u) { return __uint_as_float(u << 16); }
__device__ inline float bfhi(unsigned u) { return __uint_as_float(u & 0xffff0000u); }

// ---------------- W -> bf16 frag-order prep + cursor zeroing (merged) ----------------
__global__ __launch_bounds__(256) void k_prep(const float* __restrict__ W1, const float* __restrict__ W2,
                                              unsigned* __restrict__ W1f, unsigned* __restrict__ W2f,
                                              int* __restrict__ cbcnt) {
    int f = blockIdx.x;
    int t = threadIdx.x;
    if (f >= 20) {  // zeroing blocks
        int i = (f - 20) * 256 + t;
        if (i < NCOARSE * CSTRIPE) cbcnt[i] = 0;
        return;
    }
    int lane = t >> 2, w = t & 3;
    if (f < 16) {
        int ks = f >> 2, ct = f & 3;
        int col = ct * 16 + (lane & 15);
        int k = ks * 32 + (lane >> 4) * 8 + 2 * w;
        W1f[(f * 64 + lane) * 4 + w] = pk2(W1[k * 64 + col], W1[(k + 1) * 64 + col]);
    } else {
        int f2 = f - 16;
        int ks = f2 >> 1, ct = f2 & 1;
        int col = ct * 16 + (lane & 15);
        int k = ks * 32 + (lane >> 4) * 8 + 2 * w;
        W2f[(f2 * 64 + lane) * 4 + w] = pk2(W2[k * 32 + col], W2[(k + 1) * 32 + col]);
    }
}

// ---------------- coarse binning: 391-bin LDS histogram, 512 chunks ----------------
__global__ __launch_bounds__(512) void k_bin(const int* __restrict__ ei, unsigned* __restrict__ pairs,
                                             int* __restrict__ cbcnt) {
    __shared__ int hist[NCOARSE];
    __shared__ int base[NCOARSE];
    int t = threadIdx.x;
    int chunk = blockIdx.x;
    int s = chunk & (CSTRIPE - 1);
    int e0 = chunk * BCHUNK;
    int e1 = e0 + BCHUNK;
    for (int i = t; i < NCOARSE; i += 512) hist[i] = 0;
    __syncthreads();
#pragma unroll 4
    for (int e = e0 + t; e < e1; e += 512) {
        atomicAdd(&hist[ei[N_EDGES + e] >> 8], 1);
    }
    __syncthreads();
    for (int i = t; i < NCOARSE; i += 512) {
        int h = hist[i];
        if (h > 0) base[i] = atomicAdd(&cbcnt[i * CSTRIPE + s], h);
        hist[i] = 0;
    }
    __syncthreads();
#pragma unroll 2
    for (int e = e0 + t; e < e1; e += 512) {
        int src = ei[e];
        int dst = ei[N_EDGES + e];
        int b = dst >> 8;
        int r = atomicAdd(&hist[b], 1);
        int pos = base[b] + r;
        if (pos < CCAP)
            pairs[(size_t)(b * CSTRIPE + s) * CCAP + pos] = ((unsigned)src << 8) | (unsigned)(dst & 255);
    }
}

// ---------------- per-coarse-bin counting sort + degree-sorted slots ----------------
// outputs: cols (edges grouped by node, slot order), rpc[slot]=(start,cnt),
//          nodeof[slot]=node, invs[node]
__global__ __launch_bounds__(256) void k_csr(const unsigned* __restrict__ pairs, const int* __restrict__ cbcnt,
                                             int* __restrict__ cols, int2* __restrict__ rpc,
                                             int* __restrict__ nodeof, float* __restrict__ invs) {
    __shared__ unsigned ep[CSTRIDE];
    __shared__ unsigned srt[CSTRIDE];
    __shared__ int scnt[CSTRIPE];
    __shared__ int sbase[CSTRIPE + 1];
    __shared__ int cnt[CB_NODES];
    __shared__ int cur[CB_NODES];
    __shared__ int dh[64];
    __shared__ int dcur[64];
    __shared__ int sortcnt[CB_NODES];
    __shared__ int rankof[CB_NODES];
    __shared__ int sstart[CB_NODES];
    __shared__ int wsum2[4];
    int t = threadIdx.x;
    int b = blockIdx.x;
    if (t < CSTRIPE) {
        int c = cbcnt[b * CSTRIPE + t];
        scnt[t] = (c < CCAP) ? c : CCAP;
    }
    cnt[t] = 0;
    if (t < 64) dh[t] = 0;
    __syncthreads();
    if (t == 0) {
        int acc = 0;
#pragma unroll
        for (int s = 0; s < CSTRIPE; ++s) { sbase[s] = acc; acc += scnt[s]; }
        sbase[CSTRIPE] = acc;
    }
    __syncthreads();
    int n = sbase[CSTRIPE];
    // concat stripes into ep (vectorized loads)
#pragma unroll
    for (int s = 0; s < CSTRIPE; ++s) {
        int cs = scnt[s];
        const unsigned* sp = pairs + (size_t)(b * CSTRIPE + s) * CCAP;
        const uint4* sp4 = (const uint4*)sp;
        int base = sbase[s];
        int cs4 = cs >> 2;
        for (int i = t; i < cs4; i += 256) {
            uint4 v = sp4[i];
            int o = base + i * 4;
            ep[o] = v.x; ep[o + 1] = v.y; ep[o + 2] = v.z; ep[o + 3] = v.w;
        }
        for (int i = cs4 * 4 + t; i < cs; i += 256) ep[base + i] = sp[i];
    }
    __syncthreads();
    for (int i = t; i < n; i += 256) atomicAdd(&cnt[ep[i] & 255u], 1);
    __syncthreads();
    int d = cnt[t];
    int dc = (d < 63) ? d : 63;
    atomicAdd(&dh[dc], 1);
    __syncthreads();
    if (t < 64) {  // degree-histogram exclusive scan -> running rank cursors
        int c = dh[t];
        int v = c;
#pragma unroll
        for (int off = 1; off < 64; off <<= 1) {
            int u = __shfl_up(v, off, 64);
            if (t >= off) v += u;
        }
        dcur[t] = v - c;
    }
    __syncthreads();
    int rank = atomicAdd(&dcur[dc], 1);  // slot of node t within bin (degree-ascending)
    rankof[t] = rank;
    sortcnt[rank] = d;
    __syncthreads();
    {  // exclusive prefix over slot-ordered counts
        int c2 = sortcnt[t];
        int v2 = c2;
#pragma unroll
        for (int off = 1; off < 64; off <<= 1) {
            int u = __shfl_up(v2, off, 64);
            if ((t & 63) >= off) v2 += u;
        }
        if ((t & 63) == 63) wsum2[t >> 6] = v2;
        __syncthreads();
        int woff = 0;
        for (int w = 0; w < (t >> 6); ++w) woff += wsum2[w];
        sstart[t] = woff + v2 - c2;
    }
    __syncthreads();
    {
        int p = rankof[t];
        int st = sstart[p];
        cur[t] = st;
        int node = b * CB_NODES + t;
        int slot = b * CB_NODES + p;
        rpc[slot] = make_int2(b * CSTRIDE + st, d);
        nodeof[slot] = node;
        if (node < N_NODES) invs[node] = rsqrtf((float)(d + 1));
    }
    __syncthreads();
    for (int i = t; i < n; i += 256) {
        unsigned p = ep[i];
        int f = p & 255u;
        int pos = atomicAdd(&cur[f], 1);
        srt[pos] = p >> 8;
    }
    __syncthreads();
    int* outp = cols + (size_t)b * CSTRIDE;
    uint4* outp4 = (uint4*)outp;
    int n4 = n >> 2;
    for (int i = t; i < n4; i += 256) {
        int o = i * 4;
        outp4[i] = make_uint4(srt[o], srt[o + 1], srt[o + 2], srt[o + 3]);
    }
    for (int i = n4 * 4 + t; i < n; i += 256) outp[i] = (int)srt[i];
}

// ---------------- GEMM1 (MFMA bf16): [100000,128]f32 @ W1f -> bf16 hs1, scale invs ----------------
__global__ __launch_bounds__(256) void k_gemm1(const float* __restrict__ X, const uint4* __restrict__ W1f,
                                               const float* __restrict__ invs, unsigned short* __restrict__ out) {
    __shared__ unsigned short lt[4][16][72];
    int t = threadIdx.x;
    int w = t >> 6, l = t & 63;
    int strip = blockIdx.x * 4 + w;
    if (strip >= NSTRIPS) return;
    const float* xrow = X + (size_t)(strip * 16 + (l & 15)) * 128;
    f32x4 acc[4];
#pragma unroll
    for (int ct = 0; ct < 4; ++ct) acc[ct] = (f32x4){0.f, 0.f, 0.f, 0.f};
#pragma unroll
    for (int ks = 0; ks < 4; ++ks) {
        int kk = ks * 32 + (l >> 4) * 8;
        float4 xa = *(const float4*)(xrow + kk);
        float4 xb = *(const float4*)(xrow + kk + 4);
        Frag fa;
        fa.q = make_uint4(pk2(xa.x, xa.y), pk2(xa.z, xa.w), pk2(xb.x, xb.y), pk2(xb.z, xb.w));
#pragma unroll
        for (int ct = 0; ct < 4; ++ct) {
            Frag fb; fb.q = W1f[(ks * 4 + ct) * 64 + l];
            acc[ct] = __builtin_amdgcn_mfma_f32_16x16x32_bf16(fa.s, fb.s, acc[ct], 0, 0, 0);
        }
    }
    int rbase = strip * 16 + (l >> 4) * 4;
    float iv0 = invs[rbase], iv1 = invs[rbase + 1], iv2 = invs[rbase + 2], iv3 = invs[rbase + 3];
#pragma unroll
    for (int ct = 0; ct < 4; ++ct) {
        int cc = ct * 16 + (l & 15);
        int rr = (l >> 4) * 4;
        lt[w][rr + 0][cc] = f2bf(acc[ct][0] * iv0);
        lt[w][rr + 1][cc] = f2bf(acc[ct][1] * iv1);
        lt[w][rr + 2][cc] = f2bf(acc[ct][2] * iv2);
        lt[w][rr + 3][cc] = f2bf(acc[ct][3] * iv3);
    }
    uint4* og = (uint4*)(out + (size_t)strip * 16 * 64);
#pragma unroll
    for (int it = 0; it < 2; ++it) {
        int idx = it * 64 + l;
        int row = idx >> 3, seg = idx & 7;
        og[idx] = *(const uint4*)&lt[w][row][seg * 8];
    }
}

// ---------------- Layer1 fused: slot-ordered SpMM gather (8 lanes/node) + ReLU + MFMA gemm2 ----------------
__global__ __launch_bounds__(256) void k_l1(const unsigned short* __restrict__ hs, const int2* __restrict__ rpc,
                                            const int* __restrict__ col, const int* __restrict__ nodeof,
                                            const float* __restrict__ invs,
                                            const float* __restrict__ b1, const uint4* __restrict__ W2f,
                                            unsigned short* __restrict__ out) {
    __shared__ unsigned short hsh[32][72];
    __shared__ float ivsh[32];
    __shared__ int ndsh[32];
    __shared__ uint4 w2sh[256];
    int t = threadIdx.x;
    w2sh[t] = W2f[t];
    int l = t & 7;
    int g = t >> 3;
    int slot = blockIdx.x * 32 + g;
    int2 rc = rpc[slot];
    int node = nodeof[slot];
    int ps = rc.x, pe = rc.x + rc.y;
    const uint4* hv = (const uint4*)hs;
    float a0 = 0.f, a1 = 0.f, a2 = 0.f, a3 = 0.f, a4 = 0.f, a5 = 0.f, a6 = 0.f, a7 = 0.f;
    int p = ps;
    for (; p + 4 <= pe; p += 4) {
        int j0 = col[p], j1 = col[p + 1], j2 = col[p + 2], j3 = col[p + 3];
        uint4 u0 = hv[(size_t)j0 * 8 + l];
        uint4 u1 = hv[(size_t)j1 * 8 + l];
        uint4 u2 = hv[(size_t)j2 * 8 + l];
        uint4 u3 = hv[(size_t)j3 * 8 + l];
        a0 += bflo(u0.x); a1 += bfhi(u0.x); a2 += bflo(u0.y); a3 += bfhi(u0.y);
        a4 += bflo(u0.z); a5 += bfhi(u0.z); a6 += bflo(u0.w); a7 += bfhi(u0.w);
        a0 += bflo(u1.x); a1 += bfhi(u1.x); a2 += bflo(u1.y); a3 += bfhi(u1.y);
        a4 += bflo(u1.z); a5 += bfhi(u1.z); a6 += bflo(u1.w); a7 += bfhi(u1.w);
        a0 += bflo(u2.x); a1 += bfhi(u2.x); a2 += bflo(u2.y); a3 += bfhi(u2.y);
        a4 += bflo(u2.z); a5 += bfhi(u2.z); a6 += bflo(u2.w); a7 += bfhi(u2.w);
        a0 += bflo(u3.x); a1 += bfhi(u3.x); a2 += bflo(u3.y); a3 += bfhi(u3.y);
        a4 += bflo(u3.z); a5 += bfhi(u3.z); a6 += bflo(u3.w); a7 += bfhi(u3.w);
    }
    for (; p < pe; ++p) {
        uint4 u = hv[(size_t)col[p] * 8 + l];
        a0 += bflo(u.x); a1 += bfhi(u.x); a2 += bflo(u.y); a3 += bfhi(u.y);
        a4 += bflo(u.z); a5 += bfhi(u.z); a6 += bflo(u.w); a7 += bfhi(u.w);
    }
    uint4 us = hv[(size_t)node * 8 + l];
    a0 += bflo(us.x); a1 += bfhi(us.x); a2 += bflo(us.y); a3 += bfhi(us.y);
    a4 += bflo(us.z); a5 += bfhi(us.z); a6 += bflo(us.w); a7 += bfhi(us.w);
    float iv = (node < N_NODES) ? invs[node] : 0.f;
    float4 bb0 = *(const float4*)&b1[l * 8];
    float4 bb1 = *(const float4*)&b1[l * 8 + 4];
    float h0 = fmaxf(a0 * iv + bb0.x, 0.f), h1 = fmaxf(a1 * iv + bb0.y, 0.f);
    float h2 = fmaxf(a2 * iv + bb0.z, 0.f), h3 = fmaxf(a3 * iv + bb0.w, 0.f);
    float h4 = fmaxf(a4 * iv + bb1.x, 0.f), h5 = fmaxf(a5 * iv + bb1.y, 0.f);
    float h6 = fmaxf(a6 * iv + bb1.z, 0.f), h7 = fmaxf(a7 * iv + bb1.w, 0.f);
    uint4 hw;
    hw.x = pk2(h0, h1); hw.y = pk2(h2, h3); hw.z = pk2(h4, h5); hw.w = pk2(h6, h7);
    *(uint4*)&hsh[g][l * 8] = hw;
    if (l == 0) { ivsh[g] = iv; ndsh[g] = node; }
    __syncthreads();
    int wv = t >> 6, lane = t & 63;
    int rt = wv & 1, ct = wv >> 1;
    f32x4 acc = (f32x4){0.f, 0.f, 0.f, 0.f};
#pragma unroll
    for (int ks = 0; ks < 2; ++ks) {
        Frag fa; fa.q = *(const uint4*)&hsh[rt * 16 + (lane & 15)][ks * 32 + (lane >> 4) * 8];
        Frag fb; fb.q = w2sh[(ks * 2 + ct) * 64 + lane];
        acc = __builtin_amdgcn_mfma_f32_16x16x32_bf16(fa.s, fb.s, acc, 0, 0, 0);
    }
    int rl = rt * 16 + (lane >> 4) * 4;
    int cc = ct * 16 + (lane & 15);
#pragma unroll
    for (int i = 0; i < 4; ++i) {
        int nd = ndsh[rl + i];
        if (nd < N_NODES) out[(size_t)nd * 32 + cc] = f2bf(acc[i] * ivsh[rl + i]);
    }
}

// ---------------- SpMM2: slot-ordered, 4 lanes/node, uint4 gather -> f32 d_out ----------------
__global__ __launch_bounds__(256) void k_spmm2(const unsigned short* __restrict__ hs, const int2* __restrict__ rpc,
                                               const int* __restrict__ col, const int* __restrict__ nodeof,
                                               const float* __restrict__ invs,
                                               const float* __restrict__ b, float* __restrict__ out) {
    int t = threadIdx.x;
    int l = t & 3;
    int slot = blockIdx.x * 64 + (t >> 2);
    int2 rc = rpc[slot];
    int node = nodeof[slot];
    int ps = rc.x, pe = rc.x + rc.y;
    const uint4* hv = (const uint4*)hs;
    float a0 = 0.f, a1 = 0.f, a2 = 0.f, a3 = 0.f, a4 = 0.f, a5 = 0.f, a6 = 0.f, a7 = 0.f;
    int p = ps;
    for (; p + 4 <= pe; p += 4) {
        int j0 = col[p], j1 = col[p + 1], j2 = col[p + 2], j3 = col[p + 3];
        uint4 u0 = hv[(size_t)j0 * 4 + l];
        uint4 u1 = hv[(size_t)j1 * 4 + l];
        uint4 u2 = hv[(size_t)j2 * 4 + l];
        uint4 u3 = hv[(size_t)j3 * 4 + l];
        a0 += bflo(u0.x); a1 += bfhi(u0.x); a2 += bflo(u0.y); a3 += bfhi(u0.y);
        a4 += bflo(u0.z); a5 += bfhi(u0.z); a6 += bflo(u0.w); a7 += bfhi(u0.w);
        a0 += bflo(u1.x); a1 += bfhi(u1.x); a2 += bflo(u1.y); a3 += bfhi(u1.y);
        a4 += bflo(u1.z); a5 += bfhi(u1.z); a6 += bflo(u1.w); a7 += bfhi(u1.w);
        a0 += bflo(u2.x); a1 += bfhi(u2.x); a2 += bflo(u2.y); a3 += bfhi(u2.y);
        a4 += bflo(u2.z); a5 += bfhi(u2.z); a6 += bflo(u2.w); a7 += bfhi(u2.w);
        a0 += bflo(u3.x); a1 += bfhi(u3.x); a2 += bflo(u3.y); a3 += bfhi(u3.y);
        a4 += bflo(u3.z); a5 += bfhi(u3.z); a6 += bflo(u3.w); a7 += bfhi(u3.w);
    }
    for (; p < pe; ++p) {
        uint4 u = hv[(size_t)col[p] * 4 + l];
        a0 += bflo(u.x); a1 += bfhi(u.x); a2 += bflo(u.y); a3 += bfhi(u.y);
        a4 += bflo(u.z); a5 += bfhi(u.z); a6 += bflo(u.w); a7 += bfhi(u.w);
    }
    uint4 us = hv[(size_t)node * 4 + l];
    a0 += bflo(us.x); a1 += bfhi(us.x); a2 += bflo(us.y); a3 += bfhi(us.y);
    a4 += bflo(us.z); a5 += bfhi(us.z); a6 += bflo(us.w); a7 += bfhi(us.w);
    if (node >= N_NODES) return;
    float iv = invs[node];
    float4 bb0 = *(const float4*)&b[l * 8];
    float4 bb1 = *(const float4*)&b[l * 8 + 4];
    float4 oA = make_float4(a0 * iv + bb0.x, a1 * iv + bb0.y, a2 * iv + bb0.z, a3 * iv + bb0.w);
    float4 oB = make_float4(a4 * iv + bb1.x, a5 * iv + bb1.y, a6 * iv + bb1.z, a7 * iv + bb1.w);
    *(float4*)&out[(size_t)node * 32 + l * 8] = oA;
    *(float4*)&out[(size_t)node * 32 + l * 8 + 4] = oB;
}

extern "C" void kernel_launch(void* const* d_in, const int* in_sizes, int n_in,
                              void* d_out, int out_size, void* d_ws, size_t ws_size,
                              hipStream_t stream) {
    const float* x  = (const float*)d_in[0];
    const int*   ei = (const int*)d_in[1];
    const float* W1 = (const float*)d_in[2];
    const float* b1 = (const float*)d_in[3];
    const float* W2 = (const float*)d_in[4];
    const float* b2 = (const float*)d_in[5];
    float* out = (float*)d_out;

    char* ws = (char*)d_ws;
    size_t off = 0;
    auto alloc = [&](size_t bytes) -> void* {
        void* p = ws + off;
        off = (off + bytes + 255) & ~(size_t)255;
        return p;
    };
    int*            cbcnt  = (int*)alloc((size_t)NCOARSE * CSTRIPE * 4);
    float*          invs   = (float*)alloc((size_t)N_NODES * 4);
    unsigned*       pairs  = (unsigned*)alloc((size_t)NCOARSE * CSTRIPE * CCAP * 4);
    int*            cols   = (int*)alloc((size_t)NCOARSE * CSTRIDE * 4);
    int2*           rpc    = (int2*)alloc((size_t)NSLOTS * 8);
    int*            nodeof = (int*)alloc((size_t)NSLOTS * 4);
    unsigned short* hs1    = (unsigned short*)alloc((size_t)N_NODES * 64 * 2);
    unsigned short* hs2    = (unsigned short*)alloc((size_t)N_NODES * 32 * 2);
    unsigned*       W1f    = (unsigned*)alloc(16 * 64 * 16);
    unsigned*       W2f    = (unsigned*)alloc(4 * 64 * 16);

    k_prep<<<20 + (NCOARSE * CSTRIPE + 255) / 256, 256, 0, stream>>>(W1, W2, W1f, W2f, cbcnt);
    k_bin<<<BCHUNKS, 512, 0, stream>>>(ei, pairs, cbcnt);
    k_csr<<<NCOARSE, 256, 0, stream>>>(pairs, cbcnt, cols, rpc, nodeof, invs);
    k_gemm1<<<(NSTRIPS + 3) / 4, 256, 0, stream>>>(x, (const uint4*)W1f, invs, hs1);
    k_l1<<<NSLOTS / 32, 256, 0, stream>>>(hs1, rpc, cols, nodeof, invs, b1, (const uint4*)W2f, hs2);
    k_spmm2<<<NSLOTS / 64, 256, 0, stream>>>(hs2, rpc, cols, nodeof, invs, b2, out);
}

// Round 13
// 117.934 us; speedup vs baseline: 1.0328x; 1.0328x over previous
//
#include <hip/hip_runtime.h>

#define N_NODES 100000
#define N_EDGES 1600000
#define NCOARSE 391     // ceil(100000/256) coarse bins of 256 dst nodes
#define CB_NODES 256
#define NSLOTS  (NCOARSE * CB_NODES)  // 100096 slots (degree-sorted within bin)
#define CSTRIPE 8       // XCD-local striping of cursors + regions
#define CCAP    704     // per-(bin,stripe) capacity (mean 512, +8.5 sigma)
#define CSTRIDE 5632    // per-bin region stride = CSTRIPE*CCAP
#define BCHUNKS 256     // edge chunks (REVERTED: 16-entry runs = one full 64B line)
#define BCHUNK  6250    // N_EDGES/BCHUNKS exactly
#define NSTRIPS 6250    // N_NODES/16 row strips for MFMA gemm1

typedef short short8 __attribute__((ext_vector_type(8)));
typedef float f32x4 __attribute__((ext_vector_type(4)));
union Frag { uint4 q; short8 s; };

__device__ inline unsigned short f2bf(float f) {  // RNE f32 -> bf16
    unsigned u = __float_as_uint(f);
    unsigned r = u + 0x7fffu + ((u >> 16) & 1u);
    return (unsigned short)(r >> 16);
}
__device__ inline unsigned pk2(float lo, float hi) {
    return (unsigned)f2bf(lo) | ((unsigned)f2bf(hi) << 16);
}
__device__ inline float bflo(unsigned u) { return __uint_as_float(u << 16); }
__device__ inline float bfhi(unsigned u) { return __uint_as_float(u & 0xffff0000u); }

// ---------------- W -> bf16 frag-order prep + cursor zeroing (merged) ----------------
__global__ __launch_bounds__(256) void k_prep(const float* __restrict__ W1, const float* __restrict__ W2,
                                              unsigned* __restrict__ W1f, unsigned* __restrict__ W2f,
                                              int* __restrict__ cbcnt) {
    int f = blockIdx.x;
    int t = threadIdx.x;
    if (f >= 20) {  // zeroing blocks
        int i = (f - 20) * 256 + t;
        if (i < NCOARSE * CSTRIPE) cbcnt[i] = 0;
        return;
    }
    int lane = t >> 2, w = t & 3;
    if (f < 16) {
        int ks = f >> 2, ct = f & 3;
        int col = ct * 16 + (lane & 15);
        int k = ks * 32 + (lane >> 4) * 8 + 2 * w;
        W1f[(f * 64 + lane) * 4 + w] = pk2(W1[k * 64 + col], W1[(k + 1) * 64 + col]);
    } else {
        int f2 = f - 16;
        int ks = f2 >> 1, ct = f2 & 1;
        int col = ct * 16 + (lane & 15);
        int k = ks * 32 + (lane >> 4) * 8 + 2 * w;
        W2f[(f2 * 64 + lane) * 4 + w] = pk2(W2[k * 32 + col], W2[(k + 1) * 32 + col]);
    }
}

// ---------------- coarse binning: 391-bin LDS histogram, line-sized runs ----------------
__global__ __launch_bounds__(512) void k_bin(const int* __restrict__ ei, unsigned* __restrict__ pairs,
                                             int* __restrict__ cbcnt) {
    __shared__ int hist[NCOARSE];
    __shared__ int base[NCOARSE];
    int t = threadIdx.x;
    int chunk = blockIdx.x;
    int s = chunk & (CSTRIPE - 1);
    int e0 = chunk * BCHUNK;
    int e1 = e0 + BCHUNK;
    for (int i = t; i < NCOARSE; i += 512) hist[i] = 0;
    __syncthreads();
#pragma unroll 4
    for (int e = e0 + t; e < e1; e += 512) {
        atomicAdd(&hist[ei[N_EDGES + e] >> 8], 1);
    }
    __syncthreads();
    for (int i = t; i < NCOARSE; i += 512) {
        int h = hist[i];
        if (h > 0) base[i] = atomicAdd(&cbcnt[i * CSTRIPE + s], h);
        hist[i] = 0;
    }
    __syncthreads();
#pragma unroll 2
    for (int e = e0 + t; e < e1; e += 512) {
        int src = ei[e];
        int dst = ei[N_EDGES + e];
        int b = dst >> 8;
        int r = atomicAdd(&hist[b], 1);
        int pos = base[b] + r;
        if (pos < CCAP)
            pairs[(size_t)(b * CSTRIPE + s) * CCAP + pos] = ((unsigned)src << 8) | (unsigned)(dst & 255);
    }
}

// ---------------- per-coarse-bin counting sort + degree-sorted slots ----------------
__global__ __launch_bounds__(256) void k_csr(const unsigned* __restrict__ pairs, const int* __restrict__ cbcnt,
                                             int* __restrict__ cols, int2* __restrict__ rpc,
                                             int* __restrict__ nodeof, float* __restrict__ invs) {
    __shared__ unsigned ep[CSTRIDE];
    __shared__ unsigned srt[CSTRIDE];
    __shared__ int scnt[CSTRIPE];
    __shared__ int sbase[CSTRIPE + 1];
    __shared__ int cnt[CB_NODES];
    __shared__ int cur[CB_NODES];
    __shared__ int dh[64];
    __shared__ int dcur[64];
    __shared__ int sortcnt[CB_NODES];
    __shared__ int rankof[CB_NODES];
    __shared__ int sstart[CB_NODES];
    __shared__ int wsum2[4];
    int t = threadIdx.x;
    int b = blockIdx.x;
    if (t < CSTRIPE) {
        int c = cbcnt[b * CSTRIPE + t];
        scnt[t] = (c < CCAP) ? c : CCAP;
    }
    cnt[t] = 0;
    if (t < 64) dh[t] = 0;
    __syncthreads();
    if (t == 0) {
        int acc = 0;
#pragma unroll
        for (int s = 0; s < CSTRIPE; ++s) { sbase[s] = acc; acc += scnt[s]; }
        sbase[CSTRIPE] = acc;
    }
    __syncthreads();
    int n = sbase[CSTRIPE];
#pragma unroll
    for (int s = 0; s < CSTRIPE; ++s) {
        int cs = scnt[s];
        const unsigned* sp = pairs + (size_t)(b * CSTRIPE + s) * CCAP;
        const uint4* sp4 = (const uint4*)sp;
        int base = sbase[s];
        int cs4 = cs >> 2;
        for (int i = t; i < cs4; i += 256) {
            uint4 v = sp4[i];
            int o = base + i * 4;
            ep[o] = v.x; ep[o + 1] = v.y; ep[o + 2] = v.z; ep[o + 3] = v.w;
        }
        for (int i = cs4 * 4 + t; i < cs; i += 256) ep[base + i] = sp[i];
    }
    __syncthreads();
    for (int i = t; i < n; i += 256) atomicAdd(&cnt[ep[i] & 255u], 1);
    __syncthreads();
    int d = cnt[t];
    int dc = (d < 63) ? d : 63;
    atomicAdd(&dh[dc], 1);
    __syncthreads();
    if (t < 64) {  // degree-histogram exclusive scan -> running rank cursors
        int c = dh[t];
        int v = c;
#pragma unroll
        for (int off = 1; off < 64; off <<= 1) {
            int u = __shfl_up(v, off, 64);
            if (t >= off) v += u;
        }
        dcur[t] = v - c;
    }
    __syncthreads();
    int rank = atomicAdd(&dcur[dc], 1);  // slot of node t within bin (degree-ascending)
    rankof[t] = rank;
    sortcnt[rank] = d;
    __syncthreads();
    {  // exclusive prefix over slot-ordered counts
        int c2 = sortcnt[t];
        int v2 = c2;
#pragma unroll
        for (int off = 1; off < 64; off <<= 1) {
            int u = __shfl_up(v2, off, 64);
            if ((t & 63) >= off) v2 += u;
        }
        if ((t & 63) == 63) wsum2[t >> 6] = v2;
        __syncthreads();
        int woff = 0;
        for (int w = 0; w < (t >> 6); ++w) woff += wsum2[w];
        sstart[t] = woff + v2 - c2;
    }
    __syncthreads();
    {
        int p = rankof[t];
        int st = sstart[p];
        cur[t] = st;
        int node = b * CB_NODES + t;
        int slot = b * CB_NODES + p;
        rpc[slot] = make_int2(b * CSTRIDE + st, d);
        nodeof[slot] = node;
        if (node < N_NODES) invs[node] = rsqrtf((float)(d + 1));
    }
    __syncthreads();
    for (int i = t; i < n; i += 256) {
        unsigned p = ep[i];
        int f = p & 255u;
        int pos = atomicAdd(&cur[f], 1);
        srt[pos] = p >> 8;
    }
    __syncthreads();
    int* outp = cols + (size_t)b * CSTRIDE;
    uint4* outp4 = (uint4*)outp;
    int n4 = n >> 2;
    for (int i = t; i < n4; i += 256) {
        int o = i * 4;
        outp4[i] = make_uint4(srt[o], srt[o + 1], srt[o + 2], srt[o + 3]);
    }
    for (int i = n4 * 4 + t; i < n; i += 256) outp[i] = (int)srt[i];
}

// ---------------- GEMM1 (MFMA bf16): [100000,128]f32 @ W1f -> bf16 hs1, scale invs ----------------
__global__ __launch_bounds__(256) void k_gemm1(const float* __restrict__ X, const uint4* __restrict__ W1f,
                                               const float* __restrict__ invs, unsigned short* __restrict__ out) {
    __shared__ unsigned short lt[4][16][72];
    int t = threadIdx.x;
    int w = t >> 6, l = t & 63;
    int strip = blockIdx.x * 4 + w;
    if (strip >= NSTRIPS) return;
    const float* xrow = X + (size_t)(strip * 16 + (l & 15)) * 128;
    f32x4 acc[4];
#pragma unroll
    for (int ct = 0; ct < 4; ++ct) acc[ct] = (f32x4){0.f, 0.f, 0.f, 0.f};
#pragma unroll
    for (int ks = 0; ks < 4; ++ks) {
        int kk = ks * 32 + (l >> 4) * 8;
        float4 xa = *(const float4*)(xrow + kk);
        float4 xb = *(const float4*)(xrow + kk + 4);
        Frag fa;
        fa.q = make_uint4(pk2(xa.x, xa.y), pk2(xa.z, xa.w), pk2(xb.x, xb.y), pk2(xb.z, xb.w));
#pragma unroll
        for (int ct = 0; ct < 4; ++ct) {
            Frag fb; fb.q = W1f[(ks * 4 + ct) * 64 + l];
            acc[ct] = __builtin_amdgcn_mfma_f32_16x16x32_bf16(fa.s, fb.s, acc[ct], 0, 0, 0);
        }
    }
    int rbase = strip * 16 + (l >> 4) * 4;
    float iv0 = invs[rbase], iv1 = invs[rbase + 1], iv2 = invs[rbase + 2], iv3 = invs[rbase + 3];
#pragma unroll
    for (int ct = 0; ct < 4; ++ct) {
        int cc = ct * 16 + (l & 15);
        int rr = (l >> 4) * 4;
        lt[w][rr + 0][cc] = f2bf(acc[ct][0] * iv0);
        lt[w][rr + 1][cc] = f2bf(acc[ct][1] * iv1);
        lt[w][rr + 2][cc] = f2bf(acc[ct][2] * iv2);
        lt[w][rr + 3][cc] = f2bf(acc[ct][3] * iv3);
    }
    uint4* og = (uint4*)(out + (size_t)strip * 16 * 64);
#pragma unroll
    for (int it = 0; it < 2; ++it) {
        int idx = it * 64 + l;
        int row = idx >> 3, seg = idx & 7;
        og[idx] = *(const uint4*)&lt[w][row][seg * 8];
    }
}

// ---------------- Layer1 fused: slot-ordered SpMM gather (8 lanes/node) + ReLU + MFMA gemm2 ----------------
__global__ __launch_bounds__(256) void k_l1(const unsigned short* __restrict__ hs, const int2* __restrict__ rpc,
                                            const int* __restrict__ col, const int* __restrict__ nodeof,
                                            const float* __restrict__ invs,
                                            const float* __restrict__ b1, const uint4* __restrict__ W2f,
                                            unsigned short* __restrict__ out) {
    __shared__ unsigned short hsh[32][72];
    __shared__ float ivsh[32];
    __shared__ int ndsh[32];
    __shared__ uint4 w2sh[256];
    int t = threadIdx.x;
    w2sh[t] = W2f[t];
    int l = t & 7;
    int g = t >> 3;
    int slot = blockIdx.x * 32 + g;
    int2 rc = rpc[slot];
    int node = nodeof[slot];
    int ps = rc.x, pe = rc.x + rc.y;
    const uint4* hv = (const uint4*)hs;
    float a0 = 0.f, a1 = 0.f, a2 = 0.f, a3 = 0.f, a4 = 0.f, a5 = 0.f, a6 = 0.f, a7 = 0.f;
    int p = ps;
    for (; p + 4 <= pe; p += 4) {
        int j0 = col[p], j1 = col[p + 1], j2 = col[p + 2], j3 = col[p + 3];
        uint4 u0 = hv[(size_t)j0 * 8 + l];
        uint4 u1 = hv[(size_t)j1 * 8 + l];
        uint4 u2 = hv[(size_t)j2 * 8 + l];
        uint4 u3 = hv[(size_t)j3 * 8 + l];
        a0 += bflo(u0.x); a1 += bfhi(u0.x); a2 += bflo(u0.y); a3 += bfhi(u0.y);
        a4 += bflo(u0.z); a5 += bfhi(u0.z); a6 += bflo(u0.w); a7 += bfhi(u0.w);
        a0 += bflo(u1.x); a1 += bfhi(u1.x); a2 += bflo(u1.y); a3 += bfhi(u1.y);
        a4 += bflo(u1.z); a5 += bfhi(u1.z); a6 += bflo(u1.w); a7 += bfhi(u1.w);
        a0 += bflo(u2.x); a1 += bfhi(u2.x); a2 += bflo(u2.y); a3 += bfhi(u2.y);
        a4 += bflo(u2.z); a5 += bfhi(u2.z); a6 += bflo(u2.w); a7 += bfhi(u2.w);
        a0 += bflo(u3.x); a1 += bfhi(u3.x); a2 += bflo(u3.y); a3 += bfhi(u3.y);
        a4 += bflo(u3.z); a5 += bfhi(u3.z); a6 += bflo(u3.w); a7 += bfhi(u3.w);
    }
    for (; p < pe; ++p) {
        uint4 u = hv[(size_t)col[p] * 8 + l];
        a0 += bflo(u.x); a1 += bfhi(u.x); a2 += bflo(u.y); a3 += bfhi(u.y);
        a4 += bflo(u.z); a5 += bfhi(u.z); a6 += bflo(u.w); a7 += bfhi(u.w);
    }
    uint4 us = hv[(size_t)node * 8 + l];
    a0 += bflo(us.x); a1 += bfhi(us.x); a2 += bflo(us.y); a3 += bfhi(us.y);
    a4 += bflo(us.z); a5 += bfhi(us.z); a6 += bflo(us.w); a7 += bfhi(us.w);
    float iv = (node < N_NODES) ? invs[node] : 0.f;
    float4 bb0 = *(const float4*)&b1[l * 8];
    float4 bb1 = *(const float4*)&b1[l * 8 + 4];
    float h0 = fmaxf(a0 * iv + bb0.x, 0.f), h1 = fmaxf(a1 * iv + bb0.y, 0.f);
    float h2 = fmaxf(a2 * iv + bb0.z, 0.f), h3 = fmaxf(a3 * iv + bb0.w, 0.f);
    float h4 = fmaxf(a4 * iv + bb1.x, 0.f), h5 = fmaxf(a5 * iv + bb1.y, 0.f);
    float h6 = fmaxf(a6 * iv + bb1.z, 0.f), h7 = fmaxf(a7 * iv + bb1.w, 0.f);
    uint4 hw;
    hw.x = pk2(h0, h1); hw.y = pk2(h2, h3); hw.z = pk2(h4, h5); hw.w = pk2(h6, h7);
    *(uint4*)&hsh[g][l * 8] = hw;
    if (l == 0) { ivsh[g] = iv; ndsh[g] = node; }
    __syncthreads();
    int wv = t >> 6, lane = t & 63;
    int rt = wv & 1, ct = wv >> 1;
    f32x4 acc = (f32x4){0.f, 0.f, 0.f, 0.f};
#pragma unroll
    for (int ks = 0; ks < 2; ++ks) {
        Frag fa; fa.q = *(const uint4*)&hsh[rt * 16 + (lane & 15)][ks * 32 + (lane >> 4) * 8];
        Frag fb; fb.q = w2sh[(ks * 2 + ct) * 64 + lane];
        acc = __builtin_amdgcn_mfma_f32_16x16x32_bf16(fa.s, fb.s, acc, 0, 0, 0);
    }
    int rl = rt * 16 + (lane >> 4) * 4;
    int cc = ct * 16 + (lane & 15);
#pragma unroll
    for (int i = 0; i < 4; ++i) {
        int nd = ndsh[rl + i];
        if (nd < N_NODES) out[(size_t)nd * 32 + cc] = f2bf(acc[i] * ivsh[rl + i]);
    }
}

// ---------------- SpMM2: slot-ordered, 4 lanes/node, uint4 gather -> f32 d_out ----------------
__global__ __launch_bounds__(256) void k_spmm2(const unsigned short* __restrict__ hs, const int2* __restrict__ rpc,
                                               const int* __restrict__ col, const int* __restrict__ nodeof,
                                               const float* __restrict__ invs,
                                               const float* __restrict__ b, float* __restrict__ out) {
    int t = threadIdx.x;
    int l = t & 3;
    int slot = blockIdx.x * 64 + (t >> 2);
    int2 rc = rpc[slot];
    int node = nodeof[slot];
    int ps = rc.x, pe = rc.x + rc.y;
    const uint4* hv = (const uint4*)hs;
    float a0 = 0.f, a1 = 0.f, a2 = 0.f, a3 = 0.f, a4 = 0.f, a5 = 0.f, a6 = 0.f, a7 = 0.f;
    int p = ps;
    for (; p + 4 <= pe; p += 4) {
        int j0 = col[p], j1 = col[p + 1], j2 = col[p + 2], j3 = col[p + 3];
        uint4 u0 = hv[(size_t)j0 * 4 + l];
        uint4 u1 = hv[(size_t)j1 * 4 + l];
        uint4 u2 = hv[(size_t)j2 * 4 + l];
        uint4 u3 = hv[(size_t)j3 * 4 + l];
        a0 += bflo(u0.x); a1 += bfhi(u0.x); a2 += bflo(u0.y); a3 += bfhi(u0.y);
        a4 += bflo(u0.z); a5 += bfhi(u0.z); a6 += bflo(u0.w); a7 += bfhi(u0.w);
        a0 += bflo(u1.x); a1 += bfhi(u1.x); a2 += bflo(u1.y); a3 += bfhi(u1.y);
        a4 += bflo(u1.z); a5 += bfhi(u1.z); a6 += bflo(u1.w); a7 += bfhi(u1.w);
        a0 += bflo(u2.x); a1 += bfhi(u2.x); a2 += bflo(u2.y); a3 += bfhi(u2.y);
        a4 += bflo(u2.z); a5 += bfhi(u2.z); a6 += bflo(u2.w); a7 += bfhi(u2.w);
        a0 += bflo(u3.x); a1 += bfhi(u3.x); a2 += bflo(u3.y); a3 += bfhi(u3.y);
        a4 += bflo(u3.z); a5 += bfhi(u3.z); a6 += bflo(u3.w); a7 += bfhi(u3.w);
    }
    for (; p < pe; ++p) {
        uint4 u = hv[(size_t)col[p] * 4 + l];
        a0 += bflo(u.x); a1 += bfhi(u.x); a2 += bflo(u.y); a3 += bfhi(u.y);
        a4 += bflo(u.z); a5 += bfhi(u.z); a6 += bflo(u.w); a7 += bfhi(u.w);
    }
    uint4 us = hv[(size_t)node * 4 + l];
    a0 += bflo(us.x); a1 += bfhi(us.x); a2 += bflo(us.y); a3 += bfhi(us.y);
    a4 += bflo(us.z); a5 += bfhi(us.z); a6 += bflo(us.w); a7 += bfhi(us.w);
    if (node >= N_NODES) return;
    float iv = invs[node];
    float4 bb0 = *(const float4*)&b[l * 8];
    float4 bb1 = *(const float4*)&b[l * 8 + 4];
    float4 oA = make_float4(a0 * iv + bb0.x, a1 * iv + bb0.y, a2 * iv + bb0.z, a3 * iv + bb0.w);
    float4 oB = make_float4(a4 * iv + bb1.x, a5 * iv + bb1.y, a6 * iv + bb1.z, a7 * iv + bb1.w);
    *(float4*)&out[(size_t)node * 32 + l * 8] = oA;
    *(float4*)&out[(size_t)node * 32 + l * 8 + 4] = oB;
}

extern "C" void kernel_launch(void* const* d_in, const int* in_sizes, int n_in,
                              void* d_out, int out_size, void* d_ws, size_t ws_size,
                              hipStream_t stream) {
    const float* x  = (const float*)d_in[0];
    const int*   ei = (const int*)d_in[1];
    const float* W1 = (const float*)d_in[2];
    const float* b1 = (const float*)d_in[3];
    const float* W2 = (const float*)d_in[4];
    const float* b2 = (const float*)d_in[5];
    float* out = (float*)d_out;

    char* ws = (char*)d_ws;
    size_t off = 0;
    auto alloc = [&](size_t bytes) -> void* {
        void* p = ws + off;
        off = (off + bytes + 255) & ~(size_t)255;
        return p;
    };
    int*            cbcnt  = (int*)alloc((size_t)NCOARSE * CSTRIPE * 4);
    float*          invs   = (float*)alloc((size_t)N_NODES * 4);
    unsigned*       pairs  = (unsigned*)alloc((size_t)NCOARSE * CSTRIPE * CCAP * 4);
    int*            cols   = (int*)alloc((size_t)NCOARSE * CSTRIDE * 4);
    int2*           rpc    = (int2*)alloc((size_t)NSLOTS * 8);
    int*            nodeof = (int*)alloc((size_t)NSLOTS * 4);
    unsigned short* hs1    = (unsigned short*)alloc((size_t)N_NODES * 64 * 2);
    unsigned short* hs2    = (unsigned short*)alloc((size_t)N_NODES * 32 * 2);
    unsigned*       W1f    = (unsigned*)alloc(16 * 64 * 16);
    unsigned*       W2f    = (unsigned*)alloc(4 * 64 * 16);

    k_prep<<<20 + (NCOARSE * CSTRIPE + 255) / 256, 256, 0, stream>>>(W1, W2, W1f, W2f, cbcnt);
    k_bin<<<BCHUNKS, 512, 0, stream>>>(ei, pairs, cbcnt);
    k_csr<<<NCOARSE, 256, 0, stream>>>(pairs, cbcnt, cols, rpc, nodeof, invs);
    k_gemm1<<<(NSTRIPS + 3) / 4, 256, 0, stream>>>(x, (const uint4*)W1f, invs, hs1);
    k_l1<<<NSLOTS / 32, 256, 0, stream>>>(hs1, rpc, cols, nodeof, invs, b1, (const uint4*)W2f, hs2);
    k_spmm2<<<NSLOTS / 64, 256, 0, stream>>>(hs2, rpc, cols, nodeof, invs, b2, out);
}

// Round 14
// 110.156 us; speedup vs baseline: 1.1058x; 1.0706x over previous
//
#include <hip/hip_runtime.h>

#define N_NODES 100000
#define N_EDGES 1600000
#define NCOARSE 391     // ceil(100000/256) coarse bins of 256 dst nodes
#define CB_NODES 256
#define CSTRIPE 8       // XCD-local striping of cursors + regions
#define CCAP    1152    // per-(bin,stripe) capacity (padded-mean 742, +9 sigma)
#define CSTRIDE 9216    // per-bin region stride = CSTRIPE*CCAP
#define BCHUNKS 256     // edge chunks (16-entry mean runs)
#define BCHUNK  6250    // N_EDGES/BCHUNKS exactly
#define NSTRIPS 6250    // N_NODES/16 row strips for MFMA gemm1
#define SENTINEL 0xFFFFFFFFu

typedef short short8 __attribute__((ext_vector_type(8)));
typedef float f32x4 __attribute__((ext_vector_type(4)));
union Frag { uint4 q; short8 s; };

__device__ inline unsigned short f2bf(float f) {  // RNE f32 -> bf16
    unsigned u = __float_as_uint(f);
    unsigned r = u + 0x7fffu + ((u >> 16) & 1u);
    return (unsigned short)(r >> 16);
}
__device__ inline unsigned pk2(float lo, float hi) {
    return (unsigned)f2bf(lo) | ((unsigned)f2bf(hi) << 16);
}
__device__ inline float bflo(unsigned u) { return __uint_as_float(u << 16); }
__device__ inline float bfhi(unsigned u) { return __uint_as_float(u & 0xffff0000u); }

// ---------------- W -> bf16 frag-order prep + cursor zeroing (merged) ----------------
__global__ __launch_bounds__(256) void k_prep(const float* __restrict__ W1, const float* __restrict__ W2,
                                              unsigned* __restrict__ W1f, unsigned* __restrict__ W2f,
                                              int* __restrict__ cbcnt) {
    int f = blockIdx.x;
    int t = threadIdx.x;
    if (f >= 20) {  // zeroing blocks
        int i = (f - 20) * 256 + t;
        if (i < NCOARSE * CSTRIPE) cbcnt[i] = 0;
        return;
    }
    int lane = t >> 2, w = t & 3;
    if (f < 16) {
        int ks = f >> 2, ct = f & 3;
        int col = ct * 16 + (lane & 15);
        int k = ks * 32 + (lane >> 4) * 8 + 2 * w;
        W1f[(f * 64 + lane) * 4 + w] = pk2(W1[k * 64 + col], W1[(k + 1) * 64 + col]);
    } else {
        int f2 = f - 16;
        int ks = f2 >> 1, ct = f2 & 1;
        int col = ct * 16 + (lane & 15);
        int k = ks * 32 + (lane >> 4) * 8 + 2 * w;
        W2f[(f2 * 64 + lane) * 4 + w] = pk2(W2[k * 32 + col], W2[(k + 1) * 32 + col]);
    }
}

// ---------------- coarse binning: line-ALIGNED reservations + sentinel pads ----------------
__global__ __launch_bounds__(512) void k_bin(const int* __restrict__ ei, unsigned* __restrict__ pairs,
                                             int* __restrict__ cbcnt) {
    __shared__ int hist[NCOARSE];
    __shared__ int base[NCOARSE];
    int t = threadIdx.x;
    int chunk = blockIdx.x;
    int s = chunk & (CSTRIPE - 1);
    int e0 = chunk * BCHUNK;
    int e1 = e0 + BCHUNK;
    for (int i = t; i < NCOARSE; i += 512) hist[i] = 0;
    __syncthreads();
#pragma unroll 4
    for (int e = e0 + t; e < e1; e += 512) {
        atomicAdd(&hist[ei[N_EDGES + e] >> 8], 1);
    }
    __syncthreads();
    for (int i = t; i < NCOARSE; i += 512) {
        int h = hist[i];
        if (h > 0) {
            int hr = (h + 15) & ~15;  // round to 16 entries = 64B line
            int bs = atomicAdd(&cbcnt[i * CSTRIPE + s], hr);
            base[i] = bs;
            // sentinel-fill this block's pad slots (same fresh lines as real entries)
            unsigned* pp = pairs + (size_t)(i * CSTRIPE + s) * CCAP;
            int jhi = bs + hr; if (jhi > CCAP) jhi = CCAP;
            for (int j = bs + h; j < jhi; ++j) pp[j] = SENTINEL;
        }
        hist[i] = 0;
    }
    __syncthreads();
#pragma unroll 2
    for (int e = e0 + t; e < e1; e += 512) {
        int src = ei[e];
        int dst = ei[N_EDGES + e];
        int b = dst >> 8;
        int r = atomicAdd(&hist[b], 1);
        int pos = base[b] + r;
        if (pos < CCAP)
            pairs[(size_t)(b * CSTRIPE + s) * CCAP + pos] = ((unsigned)src << 8) | (unsigned)(dst & 255);
    }
}

// ---------------- per-coarse-bin counting sort (sentinel-filtered) -> cols + rpc + invs ----------------
__global__ __launch_bounds__(256) void k_csr(const unsigned* __restrict__ pairs, const int* __restrict__ cbcnt,
                                             int* __restrict__ cols, int2* __restrict__ rpc,
                                             float* __restrict__ invs) {
    __shared__ unsigned ep[CSTRIDE];
    __shared__ unsigned srt[CSTRIDE];
    __shared__ int scnt[CSTRIPE];
    __shared__ int sbase[CSTRIPE + 1];
    __shared__ int cnt[CB_NODES];
    __shared__ int cur[CB_NODES];
    __shared__ int wsum[4];
    __shared__ int nreal_sh;
    int t = threadIdx.x;
    int b = blockIdx.x;
    if (t < CSTRIPE) {
        int c = cbcnt[b * CSTRIPE + t];
        scnt[t] = (c < CCAP) ? c : CCAP;
    }
    cnt[t] = 0;
    __syncthreads();
    if (t == 0) {
        int acc = 0;
#pragma unroll
        for (int s = 0; s < CSTRIPE; ++s) { sbase[s] = acc; acc += scnt[s]; }
        sbase[CSTRIPE] = acc;
    }
    __syncthreads();
    int n = sbase[CSTRIPE];
    // concat stripes into ep (vectorized loads)
#pragma unroll
    for (int s = 0; s < CSTRIPE; ++s) {
        int cs = scnt[s];
        const unsigned* sp = pairs + (size_t)(b * CSTRIPE + s) * CCAP;
        const uint4* sp4 = (const uint4*)sp;
        int base = sbase[s];
        int cs4 = cs >> 2;
        for (int i = t; i < cs4; i += 256) {
            uint4 v = sp4[i];
            int o = base + i * 4;
            ep[o] = v.x; ep[o + 1] = v.y; ep[o + 2] = v.z; ep[o + 3] = v.w;
        }
        for (int i = cs4 * 4 + t; i < cs; i += 256) ep[base + i] = sp[i];
    }
    __syncthreads();
    for (int i = t; i < n; i += 256) {
        unsigned p = ep[i];
        if (p != SENTINEL) atomicAdd(&cnt[p & 255u], 1);
    }
    __syncthreads();
    {
        int c = cnt[t];
        int v = c;
#pragma unroll
        for (int off = 1; off < 64; off <<= 1) {
            int u = __shfl_up(v, off, 64);
            if ((t & 63) >= off) v += u;
        }
        if ((t & 63) == 63) wsum[t >> 6] = v;
        __syncthreads();
        int woff = 0;
        for (int w = 0; w < (t >> 6); ++w) woff += wsum[w];
        int excl = woff + v - c;
        cur[t] = excl;
        if (t == 255) nreal_sh = excl + c;
        int node = b * CB_NODES + t;
        if (node < N_NODES) {
            rpc[node] = make_int2(b * CSTRIDE + excl, c);
            invs[node] = rsqrtf((float)(c + 1));
        }
    }
    __syncthreads();
    for (int i = t; i < n; i += 256) {
        unsigned p = ep[i];
        if (p != SENTINEL) {
            int f = p & 255u;
            int pos = atomicAdd(&cur[f], 1);
            srt[pos] = p >> 8;
        }
    }
    __syncthreads();
    int nreal = nreal_sh;
    int* outp = cols + (size_t)b * CSTRIDE;
    uint4* outp4 = (uint4*)outp;
    int n4 = nreal >> 2;
    for (int i = t; i < n4; i += 256) {
        int o = i * 4;
        outp4[i] = make_uint4(srt[o], srt[o + 1], srt[o + 2], srt[o + 3]);
    }
    for (int i = n4 * 4 + t; i < nreal; i += 256) outp[i] = (int)srt[i];
}

// ---------------- GEMM1 (MFMA bf16): [100000,128]f32 @ W1f -> bf16 hs1, scale invs ----------------
__global__ __launch_bounds__(256) void k_gemm1(const float* __restrict__ X, const uint4* __restrict__ W1f,
                                               const float* __restrict__ invs, unsigned short* __restrict__ out) {
    __shared__ unsigned short lt[4][16][72];
    int t = threadIdx.x;
    int w = t >> 6, l = t & 63;
    int strip = blockIdx.x * 4 + w;
    if (strip >= NSTRIPS) return;
    const float* xrow = X + (size_t)(strip * 16 + (l & 15)) * 128;
    f32x4 acc[4];
#pragma unroll
    for (int ct = 0; ct < 4; ++ct) acc[ct] = (f32x4){0.f, 0.f, 0.f, 0.f};
#pragma unroll
    for (int ks = 0; ks < 4; ++ks) {
        int kk = ks * 32 + (l >> 4) * 8;
        float4 xa = *(const float4*)(xrow + kk);
        float4 xb = *(const float4*)(xrow + kk + 4);
        Frag fa;
        fa.q = make_uint4(pk2(xa.x, xa.y), pk2(xa.z, xa.w), pk2(xb.x, xb.y), pk2(xb.z, xb.w));
#pragma unroll
        for (int ct = 0; ct < 4; ++ct) {
            Frag fb; fb.q = W1f[(ks * 4 + ct) * 64 + l];
            acc[ct] = __builtin_amdgcn_mfma_f32_16x16x32_bf16(fa.s, fb.s, acc[ct], 0, 0, 0);
        }
    }
    int rbase = strip * 16 + (l >> 4) * 4;
    float iv0 = invs[rbase], iv1 = invs[rbase + 1], iv2 = invs[rbase + 2], iv3 = invs[rbase + 3];
#pragma unroll
    for (int ct = 0; ct < 4; ++ct) {
        int cc = ct * 16 + (l & 15);
        int rr = (l >> 4) * 4;
        lt[w][rr + 0][cc] = f2bf(acc[ct][0] * iv0);
        lt[w][rr + 1][cc] = f2bf(acc[ct][1] * iv1);
        lt[w][rr + 2][cc] = f2bf(acc[ct][2] * iv2);
        lt[w][rr + 3][cc] = f2bf(acc[ct][3] * iv3);
    }
    uint4* og = (uint4*)(out + (size_t)strip * 16 * 64);
#pragma unroll
    for (int it = 0; it < 2; ++it) {
        int idx = it * 64 + l;
        int row = idx >> 3, seg = idx & 7;
        og[idx] = *(const uint4*)&lt[w][row][seg * 8];
    }
}

// ---------------- Layer1 fused: SpMM gather (8 lanes/node) + ReLU + MFMA gemm2 -> hs2 bf16 ----------------
__global__ __launch_bounds__(256) void k_l1(const unsigned short* __restrict__ hs, const int2* __restrict__ rpc,
                                            const int* __restrict__ col, const float* __restrict__ invs,
                                            const float* __restrict__ b1, const uint4* __restrict__ W2f,
                                            unsigned short* __restrict__ out) {
    __shared__ unsigned short hsh[32][72];
    __shared__ float ivsh[32];
    __shared__ uint4 w2sh[256];
    int t = threadIdx.x;
    w2sh[t] = W2f[t];
    int l = t & 7;
    int g = t >> 3;
    int node = blockIdx.x * 32 + g;
    int2 rc = rpc[node];
    int ps = rc.x, pe = rc.x + rc.y;
    const uint4* hv = (const uint4*)hs;
    float a0 = 0.f, a1 = 0.f, a2 = 0.f, a3 = 0.f, a4 = 0.f, a5 = 0.f, a6 = 0.f, a7 = 0.f;
    int p = ps;
    for (; p + 4 <= pe; p += 4) {
        int j0 = col[p], j1 = col[p + 1], j2 = col[p + 2], j3 = col[p + 3];
        uint4 u0 = hv[(size_t)j0 * 8 + l];
        uint4 u1 = hv[(size_t)j1 * 8 + l];
        uint4 u2 = hv[(size_t)j2 * 8 + l];
        uint4 u3 = hv[(size_t)j3 * 8 + l];
        a0 += bflo(u0.x); a1 += bfhi(u0.x); a2 += bflo(u0.y); a3 += bfhi(u0.y);
        a4 += bflo(u0.z); a5 += bfhi(u0.z); a6 += bflo(u0.w); a7 += bfhi(u0.w);
        a0 += bflo(u1.x); a1 += bfhi(u1.x); a2 += bflo(u1.y); a3 += bfhi(u1.y);
        a4 += bflo(u1.z); a5 += bfhi(u1.z); a6 += bflo(u1.w); a7 += bfhi(u1.w);
        a0 += bflo(u2.x); a1 += bfhi(u2.x); a2 += bflo(u2.y); a3 += bfhi(u2.y);
        a4 += bflo(u2.z); a5 += bfhi(u2.z); a6 += bflo(u2.w); a7 += bfhi(u2.w);
        a0 += bflo(u3.x); a1 += bfhi(u3.x); a2 += bflo(u3.y); a3 += bfhi(u3.y);
        a4 += bflo(u3.z); a5 += bfhi(u3.z); a6 += bflo(u3.w); a7 += bfhi(u3.w);
    }
    for (; p < pe; ++p) {
        uint4 u = hv[(size_t)col[p] * 8 + l];
        a0 += bflo(u.x); a1 += bfhi(u.x); a2 += bflo(u.y); a3 += bfhi(u.y);
        a4 += bflo(u.z); a5 += bfhi(u.z); a6 += bflo(u.w); a7 += bfhi(u.w);
    }
    uint4 us = hv[(size_t)node * 8 + l];
    a0 += bflo(us.x); a1 += bfhi(us.x); a2 += bflo(us.y); a3 += bfhi(us.y);
    a4 += bflo(us.z); a5 += bfhi(us.z); a6 += bflo(us.w); a7 += bfhi(us.w);
    float iv = invs[node];
    float4 bb0 = *(const float4*)&b1[l * 8];
    float4 bb1 = *(const float4*)&b1[l * 8 + 4];
    float h0 = fmaxf(a0 * iv + bb0.x, 0.f), h1 = fmaxf(a1 * iv + bb0.y, 0.f);
    float h2 = fmaxf(a2 * iv + bb0.z, 0.f), h3 = fmaxf(a3 * iv + bb0.w, 0.f);
    float h4 = fmaxf(a4 * iv + bb1.x, 0.f), h5 = fmaxf(a5 * iv + bb1.y, 0.f);
    float h6 = fmaxf(a6 * iv + bb1.z, 0.f), h7 = fmaxf(a7 * iv + bb1.w, 0.f);
    uint4 hw;
    hw.x = pk2(h0, h1); hw.y = pk2(h2, h3); hw.z = pk2(h4, h5); hw.w = pk2(h6, h7);
    *(uint4*)&hsh[g][l * 8] = hw;
    if (l == 0) ivsh[g] = iv;
    __syncthreads();
    int wv = t >> 6, lane = t & 63;
    int rt = wv & 1, ct = wv >> 1;
    f32x4 acc = (f32x4){0.f, 0.f, 0.f, 0.f};
#pragma unroll
    for (int ks = 0; ks < 2; ++ks) {
        Frag fa; fa.q = *(const uint4*)&hsh[rt * 16 + (lane & 15)][ks * 32 + (lane >> 4) * 8];
        Frag fb; fb.q = w2sh[(ks * 2 + ct) * 64 + lane];
        acc = __builtin_amdgcn_mfma_f32_16x16x32_bf16(fa.s, fb.s, acc, 0, 0, 0);
    }
    int rl = rt * 16 + (lane >> 4) * 4;
    size_t nodeo = (size_t)(blockIdx.x * 32 + rl);
    int cc = ct * 16 + (lane & 15);
    out[(nodeo + 0) * 32 + cc] = f2bf(acc[0] * ivsh[rl + 0]);
    out[(nodeo + 1) * 32 + cc] = f2bf(acc[1] * ivsh[rl + 1]);
    out[(nodeo + 2) * 32 + cc] = f2bf(acc[2] * ivsh[rl + 2]);
    out[(nodeo + 3) * 32 + cc] = f2bf(acc[3] * ivsh[rl + 3]);
}

// ---------------- SpMM2: 4 lanes/node, uint4 gather, C=32 -> f32 d_out ----------------
__global__ __launch_bounds__(256) void k_spmm2(const unsigned short* __restrict__ hs, const int2* __restrict__ rpc,
                                               const int* __restrict__ col, const float* __restrict__ invs,
                                               const float* __restrict__ b, float* __restrict__ out) {
    int t = threadIdx.x;
    int l = t & 3;
    int node = blockIdx.x * 64 + (t >> 2);
    if (node >= N_NODES) return;
    int2 rc = rpc[node];
    int ps = rc.x, pe = rc.x + rc.y;
    const uint4* hv = (const uint4*)hs;
    float a0 = 0.f, a1 = 0.f, a2 = 0.f, a3 = 0.f, a4 = 0.f, a5 = 0.f, a6 = 0.f, a7 = 0.f;
    int p = ps;
    for (; p + 4 <= pe; p += 4) {
        int j0 = col[p], j1 = col[p + 1], j2 = col[p + 2], j3 = col[p + 3];
        uint4 u0 = hv[(size_t)j0 * 4 + l];
        uint4 u1 = hv[(size_t)j1 * 4 + l];
        uint4 u2 = hv[(size_t)j2 * 4 + l];
        uint4 u3 = hv[(size_t)j3 * 4 + l];
        a0 += bflo(u0.x); a1 += bfhi(u0.x); a2 += bflo(u0.y); a3 += bfhi(u0.y);
        a4 += bflo(u0.z); a5 += bfhi(u0.z); a6 += bflo(u0.w); a7 += bfhi(u0.w);
        a0 += bflo(u1.x); a1 += bfhi(u1.x); a2 += bflo(u1.y); a3 += bfhi(u1.y);
        a4 += bflo(u1.z); a5 += bfhi(u1.z); a6 += bflo(u1.w); a7 += bfhi(u1.w);
        a0 += bflo(u2.x); a1 += bfhi(u2.x); a2 += bflo(u2.y); a3 += bfhi(u2.y);
        a4 += bflo(u2.z); a5 += bfhi(u2.z); a6 += bflo(u2.w); a7 += bfhi(u2.w);
        a0 += bflo(u3.x); a1 += bfhi(u3.x); a2 += bflo(u3.y); a3 += bfhi(u3.y);
        a4 += bflo(u3.z); a5 += bfhi(u3.z); a6 += bflo(u3.w); a7 += bfhi(u3.w);
    }
    for (; p < pe; ++p) {
        uint4 u = hv[(size_t)col[p] * 4 + l];
        a0 += bflo(u.x); a1 += bfhi(u.x); a2 += bflo(u.y); a3 += bfhi(u.y);
        a4 += bflo(u.z); a5 += bfhi(u.z); a6 += bflo(u.w); a7 += bfhi(u.w);
    }
    uint4 us = hv[(size_t)node * 4 + l];
    a0 += bflo(us.x); a1 += bfhi(us.x); a2 += bflo(us.y); a3 += bfhi(us.y);
    a4 += bflo(us.z); a5 += bfhi(us.z); a6 += bflo(us.w); a7 += bfhi(us.w);
    float iv = invs[node];
    float4 bb0 = *(const float4*)&b[l * 8];
    float4 bb1 = *(const float4*)&b[l * 8 + 4];
    float4 oA = make_float4(a0 * iv + bb0.x, a1 * iv + bb0.y, a2 * iv + bb0.z, a3 * iv + bb0.w);
    float4 oB = make_float4(a4 * iv + bb1.x, a5 * iv + bb1.y, a6 * iv + bb1.z, a7 * iv + bb1.w);
    *(float4*)&out[(size_t)node * 32 + l * 8] = oA;
    *(float4*)&out[(size_t)node * 32 + l * 8 + 4] = oB;
}

extern "C" void kernel_launch(void* const* d_in, const int* in_sizes, int n_in,
                              void* d_out, int out_size, void* d_ws, size_t ws_size,
                              hipStream_t stream) {
    const float* x  = (const float*)d_in[0];
    const int*   ei = (const int*)d_in[1];
    const float* W1 = (const float*)d_in[2];
    const float* b1 = (const float*)d_in[3];
    const float* W2 = (const float*)d_in[4];
    const float* b2 = (const float*)d_in[5];
    float* out = (float*)d_out;

    char* ws = (char*)d_ws;
    size_t off = 0;
    auto alloc = [&](size_t bytes) -> void* {
        void* p = ws + off;
        off = (off + bytes + 255) & ~(size_t)255;
        return p;
    };
    int*            cbcnt = (int*)alloc((size_t)NCOARSE * CSTRIPE * 4);
    float*          invs  = (float*)alloc((size_t)N_NODES * 4);
    unsigned*       pairs = (unsigned*)alloc((size_t)NCOARSE * CSTRIPE * CCAP * 4);
    int*            cols  = (int*)alloc((size_t)NCOARSE * CSTRIDE * 4);
    int2*           rpc   = (int2*)alloc((size_t)N_NODES * 8);
    unsigned short* hs1   = (unsigned short*)alloc((size_t)N_NODES * 64 * 2);
    unsigned short* hs2   = (unsigned short*)alloc((size_t)N_NODES * 32 * 2);  // k_l1 reads hs1 while writing hs2
    unsigned*       W1f   = (unsigned*)alloc(16 * 64 * 16);
    unsigned*       W2f   = (unsigned*)alloc(4 * 64 * 16);

    k_prep<<<20 + (NCOARSE * CSTRIPE + 255) / 256, 256, 0, stream>>>(W1, W2, W1f, W2f, cbcnt);
    k_bin<<<BCHUNKS, 512, 0, stream>>>(ei, pairs, cbcnt);
    k_csr<<<NCOARSE, 256, 0, stream>>>(pairs, cbcnt, cols, rpc, invs);
    k_gemm1<<<(NSTRIPS + 3) / 4, 256, 0, stream>>>(x, (const uint4*)W1f, invs, hs1);
    k_l1<<<N_NODES / 32, 256, 0, stream>>>(hs1, rpc, cols, invs, b1, (const uint4*)W2f, hs2);
    k_spmm2<<<(N_NODES + 63) / 64, 256, 0, stream>>>(hs2, rpc, cols, invs, b2, out);
}

// Round 15
// 106.080 us; speedup vs baseline: 1.1483x; 1.0384x over previous
//
#include <hip/hip_runtime.h>

#define N_NODES 100000
#define N_EDGES 1600000
#define NCOARSE 391     // ceil(100000/256) coarse bins of 256 dst nodes
#define CB_NODES 256
#define CSTRIPE 8       // XCD-local striping of cursors + regions
#define CCAP    704     // per-(bin,stripe) capacity (mean 512, +8.5 sigma)
#define CSTRIDE 5632    // per-bin region stride = CSTRIPE*CCAP
#define BCHUNKS 256     // edge chunks (16-entry mean runs = one 64B line)
#define BCHUNK  6250    // N_EDGES/BCHUNKS exactly (= 2*3125 uint2)
#define NSTRIPS 6250    // N_NODES/16 row strips for MFMA gemm1

typedef short short8 __attribute__((ext_vector_type(8)));
typedef float f32x4 __attribute__((ext_vector_type(4)));
union Frag { uint4 q; short8 s; };

__device__ inline unsigned short f2bf(float f) {  // RNE f32 -> bf16
    unsigned u = __float_as_uint(f);
    unsigned r = u + 0x7fffu + ((u >> 16) & 1u);
    return (unsigned short)(r >> 16);
}
__device__ inline unsigned pk2(float lo, float hi) {
    return (unsigned)f2bf(lo) | ((unsigned)f2bf(hi) << 16);
}
__device__ inline float bflo(unsigned u) { return __uint_as_float(u << 16); }
__device__ inline float bfhi(unsigned u) { return __uint_as_float(u & 0xffff0000u); }

// ---------------- W -> bf16 frag-order prep + cursor zeroing (merged) ----------------
__global__ __launch_bounds__(256) void k_prep(const float* __restrict__ W1, const float* __restrict__ W2,
                                              unsigned* __restrict__ W1f, unsigned* __restrict__ W2f,
                                              int* __restrict__ cbcnt) {
    int f = blockIdx.x;
    int t = threadIdx.x;
    if (f >= 20) {  // zeroing blocks
        int i = (f - 20) * 256 + t;
        if (i < NCOARSE * CSTRIPE) cbcnt[i] = 0;
        return;
    }
    int lane = t >> 2, w = t & 3;
    if (f < 16) {
        int ks = f >> 2, ct = f & 3;
        int col = ct * 16 + (lane & 15);
        int k = ks * 32 + (lane >> 4) * 8 + 2 * w;
        W1f[(f * 64 + lane) * 4 + w] = pk2(W1[k * 64 + col], W1[(k + 1) * 64 + col]);
    } else {
        int f2 = f - 16;
        int ks = f2 >> 1, ct = f2 & 1;
        int col = ct * 16 + (lane & 15);
        int k = ks * 32 + (lane >> 4) * 8 + 2 * w;
        W2f[(f2 * 64 + lane) * 4 + w] = pk2(W2[k * 32 + col], W2[(k + 1) * 32 + col]);
    }
}

// ---------------- coarse binning: 391-bin LDS histogram, uint2-vectorized edge reads ----------------
__global__ __launch_bounds__(512) void k_bin(const int* __restrict__ ei, unsigned* __restrict__ pairs,
                                             int* __restrict__ cbcnt) {
    __shared__ int hist[NCOARSE];
    __shared__ int base[NCOARSE];
    int t = threadIdx.x;
    int chunk = blockIdx.x;
    int s = chunk & (CSTRIPE - 1);
    int e0 = chunk * BCHUNK;
    for (int i = t; i < NCOARSE; i += 512) hist[i] = 0;
    __syncthreads();
    const uint2* dst2 = (const uint2*)(ei + N_EDGES + e0);  // 3125 pairs
    const uint2* src2 = (const uint2*)(ei + e0);
#pragma unroll 2
    for (int i = t; i < BCHUNK / 2; i += 512) {
        uint2 d = dst2[i];
        atomicAdd(&hist[d.x >> 8], 1);
        atomicAdd(&hist[d.y >> 8], 1);
    }
    __syncthreads();
    for (int i = t; i < NCOARSE; i += 512) {
        int h = hist[i];
        if (h > 0) base[i] = atomicAdd(&cbcnt[i * CSTRIPE + s], h);
        hist[i] = 0;
    }
    __syncthreads();
#pragma unroll 2
    for (int i = t; i < BCHUNK / 2; i += 512) {
        uint2 d = dst2[i];
        uint2 sv = src2[i];
        {
            int b = d.x >> 8;
            int r = atomicAdd(&hist[b], 1);
            int pos = base[b] + r;
            if (pos < CCAP)
                pairs[(size_t)(b * CSTRIPE + s) * CCAP + pos] = (sv.x << 8) | (d.x & 255u);
        }
        {
            int b = d.y >> 8;
            int r = atomicAdd(&hist[b], 1);
            int pos = base[b] + r;
            if (pos < CCAP)
                pairs[(size_t)(b * CSTRIPE + s) * CCAP + pos] = (sv.y << 8) | (d.y & 255u);
        }
    }
}

// ---------------- per-coarse-bin counting sort -> sorted cols + rpc + invs ----------------
__global__ __launch_bounds__(256) void k_csr(const unsigned* __restrict__ pairs, const int* __restrict__ cbcnt,
                                             int* __restrict__ cols, int2* __restrict__ rpc,
                                             float* __restrict__ invs) {
    __shared__ unsigned ep[CSTRIDE];
    __shared__ unsigned srt[CSTRIDE];
    __shared__ int scnt[CSTRIPE];
    __shared__ int sbase[CSTRIPE + 1];
    __shared__ int cnt[CB_NODES];
    __shared__ int cur[CB_NODES];
    __shared__ int wsum[4];
    int t = threadIdx.x;
    int b = blockIdx.x;
    if (t < CSTRIPE) {
        int c = cbcnt[b * CSTRIPE + t];
        scnt[t] = (c < CCAP) ? c : CCAP;
    }
    cnt[t] = 0;
    __syncthreads();
    if (t == 0) {
        int acc = 0;
#pragma unroll
        for (int s = 0; s < CSTRIPE; ++s) { sbase[s] = acc; acc += scnt[s]; }
        sbase[CSTRIPE] = acc;
    }
    __syncthreads();
    int n = sbase[CSTRIPE];
    // concat stripes into ep (vectorized loads)
#pragma unroll
    for (int s = 0; s < CSTRIPE; ++s) {
        int cs = scnt[s];
        const unsigned* sp = pairs + (size_t)(b * CSTRIPE + s) * CCAP;
        const uint4* sp4 = (const uint4*)sp;
        int base = sbase[s];
        int cs4 = cs >> 2;
        for (int i = t; i < cs4; i += 256) {
            uint4 v = sp4[i];
            int o = base + i * 4;
            ep[o] = v.x; ep[o + 1] = v.y; ep[o + 2] = v.z; ep[o + 3] = v.w;
        }
        for (int i = cs4 * 4 + t; i < cs; i += 256) ep[base + i] = sp[i];
    }
    __syncthreads();
    for (int i = t; i < n; i += 256) atomicAdd(&cnt[ep[i] & 255u], 1);
    __syncthreads();
    {
        int c = cnt[t];
        int v = c;
#pragma unroll
        for (int off = 1; off < 64; off <<= 1) {
            int u = __shfl_up(v, off, 64);
            if ((t & 63) >= off) v += u;
        }
        if ((t & 63) == 63) wsum[t >> 6] = v;
        __syncthreads();
        int woff = 0;
        for (int w = 0; w < (t >> 6); ++w) woff += wsum[w];
        int excl = woff + v - c;
        cur[t] = excl;
        int node = b * CB_NODES + t;
        if (node < N_NODES) {
            rpc[node] = make_int2(b * CSTRIDE + excl, c);
            invs[node] = rsqrtf((float)(c + 1));
        }
    }
    __syncthreads();
    for (int i = t; i < n; i += 256) {
        unsigned p = ep[i];
        int f = p & 255u;
        int pos = atomicAdd(&cur[f], 1);
        srt[pos] = p >> 8;
    }
    __syncthreads();
    int* outp = cols + (size_t)b * CSTRIDE;
    uint4* outp4 = (uint4*)outp;
    int n4 = n >> 2;
    for (int i = t; i < n4; i += 256) {
        int o = i * 4;
        outp4[i] = make_uint4(srt[o], srt[o + 1], srt[o + 2], srt[o + 3]);
    }
    for (int i = n4 * 4 + t; i < n; i += 256) outp[i] = (int)srt[i];
}

// ---------------- GEMM1 (MFMA bf16): [100000,128]f32 @ W1f -> bf16 hs1, scale invs ----------------
__global__ __launch_bounds__(256) void k_gemm1(const float* __restrict__ X, const uint4* __restrict__ W1f,
                                               const float* __restrict__ invs, unsigned short* __restrict__ out) {
    __shared__ unsigned short lt[4][16][72];
    int t = threadIdx.x;
    int w = t >> 6, l = t & 63;
    int strip = blockIdx.x * 4 + w;
    if (strip >= NSTRIPS) return;
    const float* xrow = X + (size_t)(strip * 16 + (l & 15)) * 128;
    f32x4 acc[4];
#pragma unroll
    for (int ct = 0; ct < 4; ++ct) acc[ct] = (f32x4){0.f, 0.f, 0.f, 0.f};
#pragma unroll
    for (int ks = 0; ks < 4; ++ks) {
        int kk = ks * 32 + (l >> 4) * 8;
        float4 xa = *(const float4*)(xrow + kk);
        float4 xb = *(const float4*)(xrow + kk + 4);
        Frag fa;
        fa.q = make_uint4(pk2(xa.x, xa.y), pk2(xa.z, xa.w), pk2(xb.x, xb.y), pk2(xb.z, xb.w));
#pragma unroll
        for (int ct = 0; ct < 4; ++ct) {
            Frag fb; fb.q = W1f[(ks * 4 + ct) * 64 + l];
            acc[ct] = __builtin_amdgcn_mfma_f32_16x16x32_bf16(fa.s, fb.s, acc[ct], 0, 0, 0);
        }
    }
    int rbase = strip * 16 + (l >> 4) * 4;
    float iv0 = invs[rbase], iv1 = invs[rbase + 1], iv2 = invs[rbase + 2], iv3 = invs[rbase + 3];
#pragma unroll
    for (int ct = 0; ct < 4; ++ct) {
        int cc = ct * 16 + (l & 15);
        int rr = (l >> 4) * 4;
        lt[w][rr + 0][cc] = f2bf(acc[ct][0] * iv0);
        lt[w][rr + 1][cc] = f2bf(acc[ct][1] * iv1);
        lt[w][rr + 2][cc] = f2bf(acc[ct][2] * iv2);
        lt[w][rr + 3][cc] = f2bf(acc[ct][3] * iv3);
    }
    uint4* og = (uint4*)(out + (size_t)strip * 16 * 64);
#pragma unroll
    for (int it = 0; it < 2; ++it) {
        int idx = it * 64 + l;
        int row = idx >> 3, seg = idx & 7;
        og[idx] = *(const uint4*)&lt[w][row][seg * 8];
    }
}

// ---------------- Layer1 fused: SpMM gather (8 lanes/node) + ReLU + MFMA gemm2 -> hs2 bf16 ----------------
__global__ __launch_bounds__(256) void k_l1(const unsigned short* __restrict__ hs, const int2* __restrict__ rpc,
                                            const int* __restrict__ col, const float* __restrict__ invs,
                                            const float* __restrict__ b1, const uint4* __restrict__ W2f,
                                            unsigned short* __restrict__ out) {
    __shared__ unsigned short hsh[32][72];
    __shared__ float ivsh[32];
    __shared__ uint4 w2sh[256];
    int t = threadIdx.x;
    w2sh[t] = W2f[t];
    int l = t & 7;
    int g = t >> 3;
    int node = blockIdx.x * 32 + g;
    int2 rc = rpc[node];
    int ps = rc.x, pe = rc.x + rc.y;
    const uint4* hv = (const uint4*)hs;
    float a0 = 0.f, a1 = 0.f, a2 = 0.f, a3 = 0.f, a4 = 0.f, a5 = 0.f, a6 = 0.f, a7 = 0.f;
    int p = ps;
    for (; p + 4 <= pe; p += 4) {
        int j0 = col[p], j1 = col[p + 1], j2 = col[p + 2], j3 = col[p + 3];
        uint4 u0 = hv[(size_t)j0 * 8 + l];
        uint4 u1 = hv[(size_t)j1 * 8 + l];
        uint4 u2 = hv[(size_t)j2 * 8 + l];
        uint4 u3 = hv[(size_t)j3 * 8 + l];
        a0 += bflo(u0.x); a1 += bfhi(u0.x); a2 += bflo(u0.y); a3 += bfhi(u0.y);
        a4 += bflo(u0.z); a5 += bfhi(u0.z); a6 += bflo(u0.w); a7 += bfhi(u0.w);
        a0 += bflo(u1.x); a1 += bfhi(u1.x); a2 += bflo(u1.y); a3 += bfhi(u1.y);
        a4 += bflo(u1.z); a5 += bfhi(u1.z); a6 += bflo(u1.w); a7 += bfhi(u1.w);
        a0 += bflo(u2.x); a1 += bfhi(u2.x); a2 += bflo(u2.y); a3 += bfhi(u2.y);
        a4 += bflo(u2.z); a5 += bfhi(u2.z); a6 += bflo(u2.w); a7 += bfhi(u2.w);
        a0 += bflo(u3.x); a1 += bfhi(u3.x); a2 += bflo(u3.y); a3 += bfhi(u3.y);
        a4 += bflo(u3.z); a5 += bfhi(u3.z); a6 += bflo(u3.w); a7 += bfhi(u3.w);
    }
    for (; p < pe; ++p) {
        uint4 u = hv[(size_t)col[p] * 8 + l];
        a0 += bflo(u.x); a1 += bfhi(u.x); a2 += bflo(u.y); a3 += bfhi(u.y);
        a4 += bflo(u.z); a5 += bfhi(u.z); a6 += bflo(u.w); a7 += bfhi(u.w);
    }
    uint4 us = hv[(size_t)node * 8 + l];
    a0 += bflo(us.x); a1 += bfhi(us.x); a2 += bflo(us.y); a3 += bfhi(us.y);
    a4 += bflo(us.z); a5 += bfhi(us.z); a6 += bflo(us.w); a7 += bfhi(us.w);
    float iv = invs[node];
    float4 bb0 = *(const float4*)&b1[l * 8];
    float4 bb1 = *(const float4*)&b1[l * 8 + 4];
    float h0 = fmaxf(a0 * iv + bb0.x, 0.f), h1 = fmaxf(a1 * iv + bb0.y, 0.f);
    float h2 = fmaxf(a2 * iv + bb0.z, 0.f), h3 = fmaxf(a3 * iv + bb0.w, 0.f);
    float h4 = fmaxf(a4 * iv + bb1.x, 0.f), h5 = fmaxf(a5 * iv + bb1.y, 0.f);
    float h6 = fmaxf(a6 * iv + bb1.z, 0.f), h7 = fmaxf(a7 * iv + bb1.w, 0.f);
    uint4 hw;
    hw.x = pk2(h0, h1); hw.y = pk2(h2, h3); hw.z = pk2(h4, h5); hw.w = pk2(h6, h7);
    *(uint4*)&hsh[g][l * 8] = hw;
    if (l == 0) ivsh[g] = iv;
    __syncthreads();
    int wv = t >> 6, lane = t & 63;
    int rt = wv & 1, ct = wv >> 1;
    f32x4 acc = (f32x4){0.f, 0.f, 0.f, 0.f};
#pragma unroll
    for (int ks = 0; ks < 2; ++ks) {
        Frag fa; fa.q = *(const uint4*)&hsh[rt * 16 + (lane & 15)][ks * 32 + (lane >> 4) * 8];
        Frag fb; fb.q = w2sh[(ks * 2 + ct) * 64 + lane];
        acc = __builtin_amdgcn_mfma_f32_16x16x32_bf16(fa.s, fb.s, acc, 0, 0, 0);
    }
    int rl = rt * 16 + (lane >> 4) * 4;
    size_t nodeo = (size_t)(blockIdx.x * 32 + rl);
    int cc = ct * 16 + (lane & 15);
    out[(nodeo + 0) * 32 + cc] = f2bf(acc[0] * ivsh[rl + 0]);
    out[(nodeo + 1) * 32 + cc] = f2bf(acc[1] * ivsh[rl + 1]);
    out[(nodeo + 2) * 32 + cc] = f2bf(acc[2] * ivsh[rl + 2]);
    out[(nodeo + 3) * 32 + cc] = f2bf(acc[3] * ivsh[rl + 3]);
}

// ---------------- SpMM2: 4 lanes/node, uint4 gather, C=32 -> f32 d_out ----------------
__global__ __launch_bounds__(256) void k_spmm2(const unsigned short* __restrict__ hs, const int2* __restrict__ rpc,
                                               const int* __restrict__ col, const float* __restrict__ invs,
                                               const float* __restrict__ b, float* __restrict__ out) {
    int t = threadIdx.x;
    int l = t & 3;
    int node = blockIdx.x * 64 + (t >> 2);
    if (node >= N_NODES) return;
    int2 rc = rpc[node];
    int ps = rc.x, pe = rc.x + rc.y;
    const uint4* hv = (const uint4*)hs;
    float a0 = 0.f, a1 = 0.f, a2 = 0.f, a3 = 0.f, a4 = 0.f, a5 = 0.f, a6 = 0.f, a7 = 0.f;
    int p = ps;
    for (; p + 4 <= pe; p += 4) {
        int j0 = col[p], j1 = col[p + 1], j2 = col[p + 2], j3 = col[p + 3];
        uint4 u0 = hv[(size_t)j0 * 4 + l];
        uint4 u1 = hv[(size_t)j1 * 4 + l];
        uint4 u2 = hv[(size_t)j2 * 4 + l];
        uint4 u3 = hv[(size_t)j3 * 4 + l];
        a0 += bflo(u0.x); a1 += bfhi(u0.x); a2 += bflo(u0.y); a3 += bfhi(u0.y);
        a4 += bflo(u0.z); a5 += bfhi(u0.z); a6 += bflo(u0.w); a7 += bfhi(u0.w);
        a0 += bflo(u1.x); a1 += bfhi(u1.x); a2 += bflo(u1.y); a3 += bfhi(u1.y);
        a4 += bflo(u1.z); a5 += bfhi(u1.z); a6 += bflo(u1.w); a7 += bfhi(u1.w);
        a0 += bflo(u2.x); a1 += bfhi(u2.x); a2 += bflo(u2.y); a3 += bfhi(u2.y);
        a4 += bflo(u2.z); a5 += bfhi(u2.z); a6 += bflo(u2.w); a7 += bfhi(u2.w);
        a0 += bflo(u3.x); a1 += bfhi(u3.x); a2 += bflo(u3.y); a3 += bfhi(u3.y);
        a4 += bflo(u3.z); a5 += bfhi(u3.z); a6 += bflo(u3.w); a7 += bfhi(u3.w);
    }
    for (; p < pe; ++p) {
        uint4 u = hv[(size_t)col[p] * 4 + l];
        a0 += bflo(u.x); a1 += bfhi(u.x); a2 += bflo(u.y); a3 += bfhi(u.y);
        a4 += bflo(u.z); a5 += bfhi(u.z); a6 += bflo(u.w); a7 += bfhi(u.w);
    }
    uint4 us = hv[(size_t)node * 4 + l];
    a0 += bflo(us.x); a1 += bfhi(us.x); a2 += bflo(us.y); a3 += bfhi(us.y);
    a4 += bflo(us.z); a5 += bfhi(us.z); a6 += bflo(us.w); a7 += bfhi(us.w);
    float iv = invs[node];
    float4 bb0 = *(const float4*)&b[l * 8];
    float4 bb1 = *(const float4*)&b[l * 8 + 4];
    float4 oA = make_float4(a0 * iv + bb0.x, a1 * iv + bb0.y, a2 * iv + bb0.z, a3 * iv + bb0.w);
    float4 oB = make_float4(a4 * iv + bb1.x, a5 * iv + bb1.y, a6 * iv + bb1.z, a7 * iv + bb1.w);
    *(float4*)&out[(size_t)node * 32 + l * 8] = oA;
    *(float4*)&out[(size_t)node * 32 + l * 8 + 4] = oB;
}

extern "C" void kernel_launch(void* const* d_in, const int* in_sizes, int n_in,
                              void* d_out, int out_size, void* d_ws, size_t ws_size,
                              hipStream_t stream) {
    const float* x  = (const float*)d_in[0];
    const int*   ei = (const int*)d_in[1];
    const float* W1 = (const float*)d_in[2];
    const float* b1 = (const float*)d_in[3];
    const float* W2 = (const float*)d_in[4];
    const float* b2 = (const float*)d_in[5];
    float* out = (float*)d_out;

    char* ws = (char*)d_ws;
    size_t off = 0;
    auto alloc = [&](size_t bytes) -> void* {
        void* p = ws + off;
        off = (off + bytes + 255) & ~(size_t)255;
        return p;
    };
    int*            cbcnt = (int*)alloc((size_t)NCOARSE * CSTRIPE * 4);
    float*          invs  = (float*)alloc((size_t)N_NODES * 4);
    unsigned*       pairs = (unsigned*)alloc((size_t)NCOARSE * CSTRIPE * CCAP * 4);
    int*            cols  = (int*)alloc((size_t)NCOARSE * CSTRIDE * 4);
    int2*           rpc   = (int2*)alloc((size_t)N_NODES * 8);
    unsigned short* hs1   = (unsigned short*)alloc((size_t)N_NODES * 64 * 2);
    unsigned short* hs2   = (unsigned short*)alloc((size_t)N_NODES * 32 * 2);  // k_l1 reads hs1 while writing hs2
    unsigned*       W1f   = (unsigned*)alloc(16 * 64 * 16);
    unsigned*       W2f   = (unsigned*)alloc(4 * 64 * 16);

    k_prep<<<20 + (NCOARSE * CSTRIPE + 255) / 256, 256, 0, stream>>>(W1, W2, W1f, W2f, cbcnt);
    k_bin<<<BCHUNKS, 512, 0, stream>>>(ei, pairs, cbcnt);
    k_csr<<<NCOARSE, 256, 0, stream>>>(pairs, cbcnt, cols, rpc, invs);
    k_gemm1<<<(NSTRIPS + 3) / 4, 256, 0, stream>>>(x, (const uint4*)W1f, invs, hs1);
    k_l1<<<N_NODES / 32, 256, 0, stream>>>(hs1, rpc, cols, invs, b1, (const uint4*)W2f, hs2);
    k_spmm2<<<(N_NODES + 63) / 64, 256, 0, stream>>>(hs2, rpc, cols, invs, b2, out);
}

// Round 16
// 104.664 us; speedup vs baseline: 1.1638x; 1.0135x over previous
//
#include <hip/hip_runtime.h>

#define N_NODES 100000
#define N_EDGES 1600000
#define NCOARSE 391     // ceil(100000/256) coarse bins of 256 dst nodes
#define CB_NODES 256
#define CSTRIPE 8       // XCD-local striping of cursors + regions
#define CCAP    704     // per-(bin,stripe) capacity (mean 512, +8.5 sigma)
#define CSTRIDE 5632    // stripe-concat cap = CSTRIPE*CCAP
#define OSTR    6656    // per-bin OUTPUT stride (4-padded runs: 5632 + 3*256 rounded up)
#define BCHUNKS 256     // edge chunks (16-entry mean runs = one 64B line)
#define BCHUNK  6250    // N_EDGES/BCHUNKS exactly (= 2*3125 uint2)
#define NSTRIPS 6250    // N_NODES/16 row strips for MFMA gemm1
#define ZROW    N_NODES // sentinel zero row index

typedef short short8 __attribute__((ext_vector_type(8)));
typedef float f32x4 __attribute__((ext_vector_type(4)));
union Frag { uint4 q; short8 s; };

__device__ inline unsigned short f2bf(float f) {  // RNE f32 -> bf16
    unsigned u = __float_as_uint(f);
    unsigned r = u + 0x7fffu + ((u >> 16) & 1u);
    return (unsigned short)(r >> 16);
}
__device__ inline unsigned pk2(float lo, float hi) {
    return (unsigned)f2bf(lo) | ((unsigned)f2bf(hi) << 16);
}
__device__ inline float bflo(unsigned u) { return __uint_as_float(u << 16); }
__device__ inline float bfhi(unsigned u) { return __uint_as_float(u & 0xffff0000u); }

// ---------------- W -> bf16 frag prep + cursor zeroing + sentinel-row zeroing ----------------
__global__ __launch_bounds__(256) void k_prep(const float* __restrict__ W1, const float* __restrict__ W2,
                                              unsigned* __restrict__ W1f, unsigned* __restrict__ W2f,
                                              int* __restrict__ cbcnt,
                                              unsigned* __restrict__ hs1x, unsigned* __restrict__ hs2x) {
    int f = blockIdx.x;
    int t = threadIdx.x;
    if (f >= 20) {  // zeroing blocks
        int i = (f - 20) * 256 + t;
        if (i < NCOARSE * CSTRIPE) cbcnt[i] = 0;
        if (f == 20) {
            if (t < 32) hs1x[t] = 0;          // zero row ZROW of hs1 (64 bf16)
            else if (t < 48) hs2x[t - 32] = 0; // zero row ZROW of hs2 (32 bf16)
        }
        return;
    }
    int lane = t >> 2, w = t & 3;
    if (f < 16) {
        int ks = f >> 2, ct = f & 3;
        int col = ct * 16 + (lane & 15);
        int k = ks * 32 + (lane >> 4) * 8 + 2 * w;
        W1f[(f * 64 + lane) * 4 + w] = pk2(W1[k * 64 + col], W1[(k + 1) * 64 + col]);
    } else {
        int f2 = f - 16;
        int ks = f2 >> 1, ct = f2 & 1;
        int col = ct * 16 + (lane & 15);
        int k = ks * 32 + (lane >> 4) * 8 + 2 * w;
        W2f[(f2 * 64 + lane) * 4 + w] = pk2(W2[k * 32 + col], W2[(k + 1) * 32 + col]);
    }
}

// ---------------- coarse binning: 391-bin LDS histogram, uint2-vectorized edge reads ----------------
__global__ __launch_bounds__(512) void k_bin(const int* __restrict__ ei, unsigned* __restrict__ pairs,
                                             int* __restrict__ cbcnt) {
    __shared__ int hist[NCOARSE];
    __shared__ int base[NCOARSE];
    int t = threadIdx.x;
    int chunk = blockIdx.x;
    int s = chunk & (CSTRIPE - 1);
    int e0 = chunk * BCHUNK;
    for (int i = t; i < NCOARSE; i += 512) hist[i] = 0;
    __syncthreads();
    const uint2* dst2 = (const uint2*)(ei + N_EDGES + e0);  // 3125 pairs
    const uint2* src2 = (const uint2*)(ei + e0);
#pragma unroll 2
    for (int i = t; i < BCHUNK / 2; i += 512) {
        uint2 d = dst2[i];
        atomicAdd(&hist[d.x >> 8], 1);
        atomicAdd(&hist[d.y >> 8], 1);
    }
    __syncthreads();
    for (int i = t; i < NCOARSE; i += 512) {
        int h = hist[i];
        if (h > 0) base[i] = atomicAdd(&cbcnt[i * CSTRIPE + s], h);
        hist[i] = 0;
    }
    __syncthreads();
#pragma unroll 2
    for (int i = t; i < BCHUNK / 2; i += 512) {
        uint2 d = dst2[i];
        uint2 sv = src2[i];
        {
            int b = d.x >> 8;
            int r = atomicAdd(&hist[b], 1);
            int pos = base[b] + r;
            if (pos < CCAP)
                pairs[(size_t)(b * CSTRIPE + s) * CCAP + pos] = (sv.x << 8) | (d.x & 255u);
        }
        {
            int b = d.y >> 8;
            int r = atomicAdd(&hist[b], 1);
            int pos = base[b] + r;
            if (pos < CCAP)
                pairs[(size_t)(b * CSTRIPE + s) * CCAP + pos] = (sv.y << 8) | (d.y & 255u);
        }
    }
}

// ---------------- per-coarse-bin counting sort -> 4-aligned padded runs + rpc + invs ----------------
__global__ __launch_bounds__(256) void k_csr(const unsigned* __restrict__ pairs, const int* __restrict__ cbcnt,
                                             int* __restrict__ cols, int2* __restrict__ rpc,
                                             float* __restrict__ invs) {
    __shared__ unsigned ep[CSTRIDE];
    __shared__ unsigned srt[OSTR];
    __shared__ int scnt[CSTRIPE];
    __shared__ int sbase[CSTRIPE + 1];
    __shared__ int cnt[CB_NODES];
    __shared__ int cur[CB_NODES];
    __shared__ int wsum[4];
    __shared__ int ntot_sh;
    int t = threadIdx.x;
    int b = blockIdx.x;
    if (t < CSTRIPE) {
        int c = cbcnt[b * CSTRIPE + t];
        scnt[t] = (c < CCAP) ? c : CCAP;
    }
    cnt[t] = 0;
    __syncthreads();
    if (t == 0) {
        int acc = 0;
#pragma unroll
        for (int s = 0; s < CSTRIPE; ++s) { sbase[s] = acc; acc += scnt[s]; }
        sbase[CSTRIPE] = acc;
    }
    __syncthreads();
    int n = sbase[CSTRIPE];
    // concat stripes into ep (vectorized loads)
#pragma unroll
    for (int s = 0; s < CSTRIPE; ++s) {
        int cs = scnt[s];
        const unsigned* sp = pairs + (size_t)(b * CSTRIPE + s) * CCAP;
        const uint4* sp4 = (const uint4*)sp;
        int base = sbase[s];
        int cs4 = cs >> 2;
        for (int i = t; i < cs4; i += 256) {
            uint4 v = sp4[i];
            int o = base + i * 4;
            ep[o] = v.x; ep[o + 1] = v.y; ep[o + 2] = v.z; ep[o + 3] = v.w;
        }
        for (int i = cs4 * 4 + t; i < cs; i += 256) ep[base + i] = sp[i];
    }
    __syncthreads();
    for (int i = t; i < n; i += 256) atomicAdd(&cnt[ep[i] & 255u], 1);
    __syncthreads();
    int c = cnt[t];
    int pcnt = (c + 3) & ~3;  // 4-padded run length
    int sstart;
    {
        int v = pcnt;
#pragma unroll
        for (int off = 1; off < 64; off <<= 1) {
            int u = __shfl_up(v, off, 64);
            if ((t & 63) >= off) v += u;
        }
        if ((t & 63) == 63) wsum[t >> 6] = v;
        __syncthreads();
        int woff = 0;
        for (int w = 0; w < (t >> 6); ++w) woff += wsum[w];
        sstart = woff + v - pcnt;
        cur[t] = sstart;
        if (t == 255) ntot_sh = sstart + pcnt;
        int node = b * CB_NODES + t;
        if (node < N_NODES) {
            rpc[node] = make_int2(b * OSTR + sstart, c);
            invs[node] = rsqrtf((float)(c + 1));
        }
    }
    __syncthreads();
    for (int i = t; i < n; i += 256) {
        unsigned p = ep[i];
        int f = p & 255u;
        int pos = atomicAdd(&cur[f], 1);
        srt[pos] = p >> 8;
    }
    __syncthreads();
    // pad fill: <=3 sentinel cols per node (point at zero row)
    for (int j = sstart + c; j < sstart + pcnt; ++j) srt[j] = ZROW;
    __syncthreads();
    int n2 = ntot_sh;
    int* outp = cols + (size_t)b * OSTR;
    uint4* outp4 = (uint4*)outp;
    int n4 = n2 >> 2;  // n2 is a multiple of 4
    for (int i = t; i < n4; i += 256) {
        int o = i * 4;
        outp4[i] = make_uint4(srt[o], srt[o + 1], srt[o + 2], srt[o + 3]);
    }
}

// ---------------- GEMM1 (MFMA bf16): [100000,128]f32 @ W1f -> bf16 hs1, scale invs ----------------
__global__ __launch_bounds__(256) void k_gemm1(const float* __restrict__ X, const uint4* __restrict__ W1f,
                                               const float* __restrict__ invs, unsigned short* __restrict__ out) {
    __shared__ unsigned short lt[4][16][72];
    int t = threadIdx.x;
    int w = t >> 6, l = t & 63;
    int strip = blockIdx.x * 4 + w;
    if (strip >= NSTRIPS) return;
    const float* xrow = X + (size_t)(strip * 16 + (l & 15)) * 128;
    f32x4 acc[4];
#pragma unroll
    for (int ct = 0; ct < 4; ++ct) acc[ct] = (f32x4){0.f, 0.f, 0.f, 0.f};
#pragma unroll
    for (int ks = 0; ks < 4; ++ks) {
        int kk = ks * 32 + (l >> 4) * 8;
        float4 xa = *(const float4*)(xrow + kk);
        float4 xb = *(const float4*)(xrow + kk + 4);
        Frag fa;
        fa.q = make_uint4(pk2(xa.x, xa.y), pk2(xa.z, xa.w), pk2(xb.x, xb.y), pk2(xb.z, xb.w));
#pragma unroll
        for (int ct = 0; ct < 4; ++ct) {
            Frag fb; fb.q = W1f[(ks * 4 + ct) * 64 + l];
            acc[ct] = __builtin_amdgcn_mfma_f32_16x16x32_bf16(fa.s, fb.s, acc[ct], 0, 0, 0);
        }
    }
    int rbase = strip * 16 + (l >> 4) * 4;
    float iv0 = invs[rbase], iv1 = invs[rbase + 1], iv2 = invs[rbase + 2], iv3 = invs[rbase + 3];
#pragma unroll
    for (int ct = 0; ct < 4; ++ct) {
        int cc = ct * 16 + (l & 15);
        int rr = (l >> 4) * 4;
        lt[w][rr + 0][cc] = f2bf(acc[ct][0] * iv0);
        lt[w][rr + 1][cc] = f2bf(acc[ct][1] * iv1);
        lt[w][rr + 2][cc] = f2bf(acc[ct][2] * iv2);
        lt[w][rr + 3][cc] = f2bf(acc[ct][3] * iv3);
    }
    uint4* og = (uint4*)(out + (size_t)strip * 16 * 64);
#pragma unroll
    for (int it = 0; it < 2; ++it) {
        int idx = it * 64 + l;
        int row = idx >> 3, seg = idx & 7;
        og[idx] = *(const uint4*)&lt[w][row][seg * 8];
    }
}

// ---------------- Layer1 fused: SpMM gather (8 lanes/node, uint4 col) + ReLU + MFMA gemm2 ----------------
__global__ __launch_bounds__(256) void k_l1(const unsigned short* __restrict__ hs, const int2* __restrict__ rpc,
                                            const int* __restrict__ col, const float* __restrict__ invs,
                                            const float* __restrict__ b1, const uint4* __restrict__ W2f,
                                            unsigned short* __restrict__ out) {
    __shared__ unsigned short hsh[32][72];
    __shared__ float ivsh[32];
    __shared__ uint4 w2sh[256];
    int t = threadIdx.x;
    w2sh[t] = W2f[t];
    int l = t & 7;
    int g = t >> 3;
    int node = blockIdx.x * 32 + g;
    int2 rc = rpc[node];
    int ps = rc.x;
    int pe = ps + ((rc.y + 3) & ~3);  // padded run, 4-aligned
    const uint4* hv = (const uint4*)hs;
    float a0 = 0.f, a1 = 0.f, a2 = 0.f, a3 = 0.f, a4 = 0.f, a5 = 0.f, a6 = 0.f, a7 = 0.f;
    for (int p = ps; p < pe; p += 4) {
        uint4 j4 = *(const uint4*)&col[p];
        uint4 u0 = hv[(size_t)j4.x * 8 + l];
        uint4 u1 = hv[(size_t)j4.y * 8 + l];
        uint4 u2 = hv[(size_t)j4.z * 8 + l];
        uint4 u3 = hv[(size_t)j4.w * 8 + l];
        a0 += bflo(u0.x); a1 += bfhi(u0.x); a2 += bflo(u0.y); a3 += bfhi(u0.y);
        a4 += bflo(u0.z); a5 += bfhi(u0.z); a6 += bflo(u0.w); a7 += bfhi(u0.w);
        a0 += bflo(u1.x); a1 += bfhi(u1.x); a2 += bflo(u1.y); a3 += bfhi(u1.y);
        a4 += bflo(u1.z); a5 += bfhi(u1.z); a6 += bflo(u1.w); a7 += bfhi(u1.w);
        a0 += bflo(u2.x); a1 += bfhi(u2.x); a2 += bflo(u2.y); a3 += bfhi(u2.y);
        a4 += bflo(u2.z); a5 += bfhi(u2.z); a6 += bflo(u2.w); a7 += bfhi(u2.w);
        a0 += bflo(u3.x); a1 += bfhi(u3.x); a2 += bflo(u3.y); a3 += bfhi(u3.y);
        a4 += bflo(u3.z); a5 += bfhi(u3.z); a6 += bflo(u3.w); a7 += bfhi(u3.w);
    }
    uint4 us = hv[(size_t)node * 8 + l];
    a0 += bflo(us.x); a1 += bfhi(us.x); a2 += bflo(us.y); a3 += bfhi(us.y);
    a4 += bflo(us.z); a5 += bfhi(us.z); a6 += bflo(us.w); a7 += bfhi(us.w);
    float iv = invs[node];
    float4 bb0 = *(const float4*)&b1[l * 8];
    float4 bb1 = *(const float4*)&b1[l * 8 + 4];
    float h0 = fmaxf(a0 * iv + bb0.x, 0.f), h1 = fmaxf(a1 * iv + bb0.y, 0.f);
    float h2 = fmaxf(a2 * iv + bb0.z, 0.f), h3 = fmaxf(a3 * iv + bb0.w, 0.f);
    float h4 = fmaxf(a4 * iv + bb1.x, 0.f), h5 = fmaxf(a5 * iv + bb1.y, 0.f);
    float h6 = fmaxf(a6 * iv + bb1.z, 0.f), h7 = fmaxf(a7 * iv + bb1.w, 0.f);
    uint4 hw;
    hw.x = pk2(h0, h1); hw.y = pk2(h2, h3); hw.z = pk2(h4, h5); hw.w = pk2(h6, h7);
    *(uint4*)&hsh[g][l * 8] = hw;
    if (l == 0) ivsh[g] = iv;
    __syncthreads();
    int wv = t >> 6, lane = t & 63;
    int rt = wv & 1, ct = wv >> 1;
    f32x4 acc = (f32x4){0.f, 0.f, 0.f, 0.f};
#pragma unroll
    for (int ks = 0; ks < 2; ++ks) {
        Frag fa; fa.q = *(const uint4*)&hsh[rt * 16 + (lane & 15)][ks * 32 + (lane >> 4) * 8];
        Frag fb; fb.q = w2sh[(ks * 2 + ct) * 64 + lane];
        acc = __builtin_amdgcn_mfma_f32_16x16x32_bf16(fa.s, fb.s, acc, 0, 0, 0);
    }
    int rl = rt * 16 + (lane >> 4) * 4;
    size_t nodeo = (size_t)(blockIdx.x * 32 + rl);
    int cc = ct * 16 + (lane & 15);
    out[(nodeo + 0) * 32 + cc] = f2bf(acc[0] * ivsh[rl + 0]);
    out[(nodeo + 1) * 32 + cc] = f2bf(acc[1] * ivsh[rl + 1]);
    out[(nodeo + 2) * 32 + cc] = f2bf(acc[2] * ivsh[rl + 2]);
    out[(nodeo + 3) * 32 + cc] = f2bf(acc[3] * ivsh[rl + 3]);
}

// ---------------- SpMM2: 4 lanes/node, uint4 col + uint4 gather, C=32 -> f32 d_out ----------------
__global__ __launch_bounds__(256) void k_spmm2(const unsigned short* __restrict__ hs, const int2* __restrict__ rpc,
                                               const int* __restrict__ col, const float* __restrict__ invs,
                                               const float* __restrict__ b, float* __restrict__ out) {
    int t = threadIdx.x;
    int l = t & 3;
    int node = blockIdx.x * 64 + (t >> 2);
    if (node >= N_NODES) return;
    int2 rc = rpc[node];
    int ps = rc.x;
    int pe = ps + ((rc.y + 3) & ~3);
    const uint4* hv = (const uint4*)hs;
    float a0 = 0.f, a1 = 0.f, a2 = 0.f, a3 = 0.f, a4 = 0.f, a5 = 0.f, a6 = 0.f, a7 = 0.f;
    for (int p = ps; p < pe; p += 4) {
        uint4 j4 = *(const uint4*)&col[p];
        uint4 u0 = hv[(size_t)j4.x * 4 + l];
        uint4 u1 = hv[(size_t)j4.y * 4 + l];
        uint4 u2 = hv[(size_t)j4.z * 4 + l];
        uint4 u3 = hv[(size_t)j4.w * 4 + l];
        a0 += bflo(u0.x); a1 += bfhi(u0.x); a2 += bflo(u0.y); a3 += bfhi(u0.y);
        a4 += bflo(u0.z); a5 += bfhi(u0.z); a6 += bflo(u0.w); a7 += bfhi(u0.w);
        a0 += bflo(u1.x); a1 += bfhi(u1.x); a2 += bflo(u1.y); a3 += bfhi(u1.y);
        a4 += bflo(u1.z); a5 += bfhi(u1.z); a6 += bflo(u1.w); a7 += bfhi(u1.w);
        a0 += bflo(u2.x); a1 += bfhi(u2.x); a2 += bflo(u2.y); a3 += bfhi(u2.y);
        a4 += bflo(u2.z); a5 += bfhi(u2.z); a6 += bflo(u2.w); a7 += bfhi(u2.w);
        a0 += bflo(u3.x); a1 += bfhi(u3.x); a2 += bflo(u3.y); a3 += bfhi(u3.y);
        a4 += bflo(u3.z); a5 += bfhi(u3.z); a6 += bflo(u3.w); a7 += bfhi(u3.w);
    }
    uint4 us = hv[(size_t)node * 4 + l];
    a0 += bflo(us.x); a1 += bfhi(us.x); a2 += bflo(us.y); a3 += bfhi(us.y);
    a4 += bflo(us.z); a5 += bfhi(us.z); a6 += bflo(us.w); a7 += bfhi(us.w);
    float iv = invs[node];
    float4 bb0 = *(const float4*)&b[l * 8];
    float4 bb1 = *(const float4*)&b[l * 8 + 4];
    float4 oA = make_float4(a0 * iv + bb0.x, a1 * iv + bb0.y, a2 * iv + bb0.z, a3 * iv + bb0.w);
    float4 oB = make_float4(a4 * iv + bb1.x, a5 * iv + bb1.y, a6 * iv + bb1.z, a7 * iv + bb1.w);
    *(float4*)&out[(size_t)node * 32 + l * 8] = oA;
    *(float4*)&out[(size_t)node * 32 + l * 8 + 4] = oB;
}

extern "C" void kernel_launch(void* const* d_in, const int* in_sizes, int n_in,
                              void* d_out, int out_size, void* d_ws, size_t ws_size,
                              hipStream_t stream) {
    const float* x  = (const float*)d_in[0];
    const int*   ei = (const int*)d_in[1];
    const float* W1 = (const float*)d_in[2];
    const float* b1 = (const float*)d_in[3];
    const float* W2 = (const float*)d_in[4];
    const float* b2 = (const float*)d_in[5];
    float* out = (float*)d_out;

    char* ws = (char*)d_ws;
    size_t off = 0;
    auto alloc = [&](size_t bytes) -> void* {
        void* p = ws + off;
        off = (off + bytes + 255) & ~(size_t)255;
        return p;
    };
    int*            cbcnt = (int*)alloc((size_t)NCOARSE * CSTRIPE * 4);
    float*          invs  = (float*)alloc((size_t)N_NODES * 4);
    unsigned*       pairs = (unsigned*)alloc((size_t)NCOARSE * CSTRIPE * CCAP * 4);
    int*            cols  = (int*)alloc((size_t)NCOARSE * OSTR * 4);
    int2*           rpc   = (int2*)alloc((size_t)N_NODES * 8);
    unsigned short* hs1   = (unsigned short*)alloc((size_t)(N_NODES + 1) * 64 * 2);  // +1 sentinel zero row
    unsigned short* hs2   = (unsigned short*)alloc((size_t)(N_NODES + 1) * 32 * 2);  // +1 sentinel zero row
    unsigned*       W1f   = (unsigned*)alloc(16 * 64 * 16);
    unsigned*       W2f   = (unsigned*)alloc(4 * 64 * 16);

    unsigned* hs1x = (unsigned*)(hs1 + (size_t)ZROW * 64);
    unsigned* hs2x = (unsigned*)(hs2 + (size_t)ZROW * 32);

    k_prep<<<20 + (NCOARSE * CSTRIPE + 255) / 256, 256, 0, stream>>>(W1, W2, W1f, W2f, cbcnt, hs1x, hs2x);
    k_bin<<<BCHUNKS, 512, 0, stream>>>(ei, pairs, cbcnt);
    k_csr<<<NCOARSE, 256, 0, stream>>>(pairs, cbcnt, cols, rpc, invs);
    k_gemm1<<<(NSTRIPS + 3) / 4, 256, 0, stream>>>(x, (const uint4*)W1f, invs, hs1);
    k_l1<<<N_NODES / 32, 256, 0, stream>>>(hs1, rpc, cols, invs, b1, (const uint4*)W2f, hs2);
    k_spmm2<<<(N_NODES + 63) / 64, 256, 0, stream>>>(hs2, rpc, cols, invs, b2, out);
}